// Round 1
// baseline (1433.075 us; speedup 1.0000x reference)
//
#include <hip/hip_runtime.h>
#include <math.h>

// ---------------------------------------------------------------------------
// TGN GraphAttentionEmbedding:
//   h = [x, feats]                         (N,128)
//   q/k/v/skip = h @ W* + b*              4x (N,128)
//   edge_attr = [cos((lu[src]-t)*tw+tb), msg]   (E,128)
//   e = edge_attr @ We                     (E,128)
//   alpha = sum_head(q[dst]*(k[src]+e))/4  (E,8), segment-softmax over dst
//   out = segsum((v[src]+e)*a) + skip
// ---------------------------------------------------------------------------

struct NodeGemmArgs {
  const float* W[4];
  const float* b[4];
  float* outp[4];
};

// ---- sort edges by dst: histogram -> scan -> scatter ----------------------
__global__ void k_hist(const int* __restrict__ ei, int* __restrict__ counts, int E) {
  int i = blockIdx.x * 256 + threadIdx.x;
  if (i < E) atomicAdd(&counts[ei[E + i]], 1);
}

__global__ __launch_bounds__(1024) void k_scan(const int* __restrict__ counts,
                                               int* __restrict__ offs,
                                               int* __restrict__ cursor, int N) {
  __shared__ int sums[1024];
  const int t = threadIdx.x;
  const int chunk = (N + 1023) / 1024;
  const int lo = t * chunk;
  const int hi = (lo + chunk < N) ? lo + chunk : N;
  int s = 0;
  for (int i = lo; i < hi; ++i) s += counts[i];
  sums[t] = s;
  __syncthreads();
  // Hillis-Steele inclusive scan
  for (int d = 1; d < 1024; d <<= 1) {
    int val = (t >= d) ? sums[t - d] : 0;
    __syncthreads();
    sums[t] += val;
    __syncthreads();
  }
  int run = (t == 0) ? 0 : sums[t - 1];
  for (int i = lo; i < hi; ++i) {
    offs[i] = run;
    cursor[i] = run;
    run += counts[i];
  }
  if (t == 1023) offs[N] = sums[1023];
}

__global__ void k_scatter(const int* __restrict__ ei, int* __restrict__ cursor,
                          int* __restrict__ sorted, int E) {
  int i = blockIdx.x * 256 + threadIdx.x;
  if (i < E) {
    int pos = atomicAdd(&cursor[ei[E + i]], 1);
    sorted[pos] = i;
  }
}

// ---- node GEMMs: thread owns one W column (128 VGPRs), loops nodes --------
__global__ __launch_bounds__(128) void k_node_gemm(
    const float* __restrict__ x, const float* __restrict__ feats,
    NodeGemmArgs args, int N) {
  const int o = threadIdx.x;              // output column 0..127
  const int which = blockIdx.y;           // 0=q 1=k 2=v 3=skip
  const float* __restrict__ W = args.W[which];
  const float bias = args.b[which][o];
  float* __restrict__ outp = args.outp[which];
  float wcol[128];
#pragma unroll
  for (int k = 0; k < 128; ++k) wcol[k] = W[k * 128 + o];
  __shared__ float hlds[4][128];
  const int n0 = blockIdx.x * 64;
  for (int nn = 0; nn < 64; nn += 4) {
#pragma unroll
    for (int j = 0; j < 4; ++j) {
      int n = n0 + nn + j;
      float hv = 0.f;
      if (n < N) hv = (o < 64) ? x[(size_t)n * 64 + o]
                               : feats[(size_t)n * 64 + (o - 64)];
      hlds[j][o] = hv;
    }
    __syncthreads();
#pragma unroll
    for (int j = 0; j < 4; ++j) {
      int n = n0 + nn + j;
      if (n < N) {
        const float4* h4 = (const float4*)(&hlds[j][0]);
        float acc = bias;
#pragma unroll
        for (int k4 = 0; k4 < 32; ++k4) {
          float4 hv = h4[k4];
          acc = fmaf(hv.x, wcol[4 * k4 + 0], acc);
          acc = fmaf(hv.y, wcol[4 * k4 + 1], acc);
          acc = fmaf(hv.z, wcol[4 * k4 + 2], acc);
          acc = fmaf(hv.w, wcol[4 * k4 + 3], acc);
        }
        outp[(size_t)n * 128 + o] = acc;
      }
    }
    __syncthreads();
  }
}

// ---- edge kernel: edge_attr build + e = edge_attr@We + alpha --------------
__global__ __launch_bounds__(256) void k_edge(
    const float* __restrict__ lu, const int* __restrict__ ei,
    const float* __restrict__ t, const float* __restrict__ msg,
    const float* __restrict__ tw, const float* __restrict__ tb,
    const float* __restrict__ We, const float* __restrict__ q,
    const float* __restrict__ kb, float* __restrict__ e_buf,
    float* __restrict__ alpha, int E) {
  const int half = threadIdx.x >> 7;      // which of 2 concurrent edges
  const int o = threadIdx.x & 127;        // output column
  float wcol[128];
#pragma unroll
  for (int k = 0; k < 128; ++k) wcol[k] = We[k * 128 + o];
  const float twv = (o < 64) ? tw[o] : 0.f;
  const float tbv = (o < 64) ? tb[o] : 0.f;
  __shared__ float ea[2][128];
  const int base = blockIdx.x * 64;
  for (int it = 0; it < 32; ++it) {
    const int eid = base + it * 2 + half;
    int src = 0, dst = 0;
    if (eid < E) {
      src = ei[eid];
      dst = ei[E + eid];
      float av;
      if (o < 64) av = __cosf((lu[src] - t[eid]) * twv + tbv);
      else        av = msg[(size_t)eid * 64 + (o - 64)];
      ea[half][o] = av;
    }
    __syncthreads();
    if (eid < E) {
      const float4* a4 = (const float4*)(&ea[half][0]);
      float acc = 0.f;
#pragma unroll
      for (int k4 = 0; k4 < 32; ++k4) {
        float4 av = a4[k4];
        acc = fmaf(av.x, wcol[4 * k4 + 0], acc);
        acc = fmaf(av.y, wcol[4 * k4 + 1], acc);
        acc = fmaf(av.z, wcol[4 * k4 + 2], acc);
        acc = fmaf(av.w, wcol[4 * k4 + 3], acc);
      }
      e_buf[(size_t)eid * 128 + o] = acc;
      // alpha: head h = o/16, reduce q[dst][o]*(k[src][o]+e[o]) over 16 lanes
      float part = q[(size_t)dst * 128 + o] * (kb[(size_t)src * 128 + o] + acc);
      part += __shfl_xor(part, 1);
      part += __shfl_xor(part, 2);
      part += __shfl_xor(part, 4);
      part += __shfl_xor(part, 8);
      if ((o & 15) == 0) alpha[(size_t)eid * 8 + (o >> 4)] = part * 0.25f;
    }
    __syncthreads();
  }
}

// ---- per-dst aggregation: one wave per node -------------------------------
__global__ __launch_bounds__(256) void k_agg(
    const int* __restrict__ ei, const int* __restrict__ offs,
    const int* __restrict__ sorted, const float* __restrict__ alpha,
    const float* __restrict__ e_buf, const float* __restrict__ vb,
    float* __restrict__ out, int N) {
  const int wave = threadIdx.x >> 6;
  const int lane = threadIdx.x & 63;
  const int n = blockIdx.x * 4 + wave;
  if (n >= N) return;
  const int off = offs[n], end = offs[n + 1];
  const int h1 = lane >> 4;               // heads for o1=lane (0..3)
  const int h2 = h1 + 4;                  // heads for o2=lane+64 (4..7)
  const int o1 = lane, o2 = lane + 64;
  float acc1 = 0.f, acc2 = 0.f;
  if (end > off) {
    float m1 = -1e30f, m2 = -1e30f;
    for (int i = off; i < end; ++i) {
      int eid = sorted[i];
      m1 = fmaxf(m1, alpha[(size_t)eid * 8 + h1]);
      m2 = fmaxf(m2, alpha[(size_t)eid * 8 + h2]);
    }
    float s1 = 0.f, s2 = 0.f;
    for (int i = off; i < end; ++i) {
      int eid = sorted[i];
      s1 += __expf(alpha[(size_t)eid * 8 + h1] - m1);
      s2 += __expf(alpha[(size_t)eid * 8 + h2] - m2);
    }
    const float r1 = 1.f / (s1 + 1e-16f);
    const float r2 = 1.f / (s2 + 1e-16f);
    for (int i = off; i < end; ++i) {
      int eid = sorted[i];
      int src = ei[eid];
      float a1 = __expf(alpha[(size_t)eid * 8 + h1] - m1) * r1;
      float a2 = __expf(alpha[(size_t)eid * 8 + h2] - m2) * r2;
      acc1 += (vb[(size_t)src * 128 + o1] + e_buf[(size_t)eid * 128 + o1]) * a1;
      acc2 += (vb[(size_t)src * 128 + o2] + e_buf[(size_t)eid * 128 + o2]) * a2;
    }
  }
  // out already holds skip (h@Wskip + bskip) from k_node_gemm
  out[(size_t)n * 128 + o1] += acc1;
  out[(size_t)n * 128 + o2] += acc2;
}

extern "C" void kernel_launch(void* const* d_in, const int* in_sizes, int n_in,
                              void* d_out, int out_size, void* d_ws, size_t ws_size,
                              hipStream_t stream) {
  const float* feats = (const float*)d_in[0];
  const float* x     = (const float*)d_in[1];
  const float* lu    = (const float*)d_in[2];
  const int*   ei    = (const int*)d_in[3];   // [2,E] int32: row0=src row1=dst
  const float* t     = (const float*)d_in[4];
  const float* msg   = (const float*)d_in[5];
  const float* tw    = (const float*)d_in[6];
  const float* tb    = (const float*)d_in[7];
  const float* Wq    = (const float*)d_in[8];
  const float* bq    = (const float*)d_in[9];
  const float* Wk    = (const float*)d_in[10];
  const float* bk    = (const float*)d_in[11];
  const float* Wv    = (const float*)d_in[12];
  const float* bv    = (const float*)d_in[13];
  const float* We    = (const float*)d_in[14];
  const float* Wskip = (const float*)d_in[15];
  const float* bskip = (const float*)d_in[16];
  float* out = (float*)d_out;
  const int N = in_sizes[2];   // last_update
  const int E = in_sizes[4];   // t

  char* ws = (char*)d_ws;
  float* qb    = (float*)ws; ws += (size_t)N * 128 * 4;
  float* kbuf  = (float*)ws; ws += (size_t)N * 128 * 4;
  float* vb    = (float*)ws; ws += (size_t)N * 128 * 4;
  float* e_buf = (float*)ws; ws += (size_t)E * 128 * 4;
  float* alpha = (float*)ws; ws += (size_t)E * 8 * 4;
  int* counts  = (int*)ws;   ws += (size_t)(N + 1) * 4;
  int* offs    = (int*)ws;   ws += (size_t)(N + 1) * 4;
  int* cursor  = (int*)ws;   ws += (size_t)N * 4;
  int* sorted  = (int*)ws;   ws += (size_t)E * 4;

  hipMemsetAsync(counts, 0, (size_t)(N + 1) * 4, stream);
  k_hist<<<(E + 255) / 256, 256, 0, stream>>>(ei, counts, E);
  k_scan<<<1, 1024, 0, stream>>>(counts, offs, cursor, N);
  k_scatter<<<(E + 255) / 256, 256, 0, stream>>>(ei, cursor, sorted, E);

  NodeGemmArgs a;
  a.W[0] = Wq;    a.W[1] = Wk;    a.W[2] = Wv;    a.W[3] = Wskip;
  a.b[0] = bq;    a.b[1] = bk;    a.b[2] = bv;    a.b[3] = bskip;
  a.outp[0] = qb; a.outp[1] = kbuf; a.outp[2] = vb; a.outp[3] = out;
  dim3 g3((N + 63) / 64, 4);
  k_node_gemm<<<g3, 128, 0, stream>>>(x, feats, a, N);

  k_edge<<<(E + 63) / 64, 256, 0, stream>>>(lu, ei, t, msg, tw, tb, We,
                                            qb, kbuf, e_buf, alpha, E);
  k_agg<<<(N + 3) / 4, 256, 0, stream>>>(ei, offs, sorted, alpha, e_buf, vb,
                                         out, N);
}

// Round 2
// 506.688 us; speedup vs baseline: 2.8283x; 2.8283x over previous
//
#include <hip/hip_runtime.h>
#include <math.h>

// ---------------------------------------------------------------------------
// TGN GraphAttentionEmbedding, MFMA bf16 version.
//   h = [x, feats]  (N,128);  q/k/v/skip = h@W*+b*  (MFMA, bf16 out except skip)
//   edge_attr = [cos((lu[src]-t)*tw+tb), msg]; e = edge_attr@We (MFMA, bf16)
//   alpha = sum_head(q[dst]*(k[src]+e))/4 ; segment softmax over dst; aggregate
// ---------------------------------------------------------------------------

typedef __attribute__((ext_vector_type(8))) short bf16x8;
typedef __attribute__((ext_vector_type(4))) float f32x4;

__device__ inline short f2bf(float f) {
  unsigned u = __float_as_uint(f);
  u += 0x7fff + ((u >> 16) & 1);     // round-to-nearest-even
  return (short)(u >> 16);
}
__device__ inline float bf2f(short s) {
  return __uint_as_float(((unsigned)(unsigned short)s) << 16);
}

// ---- sort edges by dst ----------------------------------------------------
__global__ void k_hist(const int* __restrict__ ei, int* __restrict__ counts, int E) {
  int i = blockIdx.x * 256 + threadIdx.x;
  if (i < E) atomicAdd(&counts[ei[E + i]], 1);
}

__global__ __launch_bounds__(1024) void k_bsum(const int* __restrict__ counts,
                                               int* __restrict__ bsum, int N) {
  int i = blockIdx.x * 1024 + threadIdx.x;
  int v = (i < N) ? counts[i] : 0;
  for (int d = 32; d; d >>= 1) v += __shfl_down(v, d);
  __shared__ int ws_[16];
  int lane = threadIdx.x & 63, wv = threadIdx.x >> 6;
  if (lane == 0) ws_[wv] = v;
  __syncthreads();
  if (threadIdx.x == 0) {
    int s = 0;
    for (int j = 0; j < 16; ++j) s += ws_[j];
    bsum[blockIdx.x] = s;
  }
}

__global__ __launch_bounds__(128) void k_bscan(const int* __restrict__ bsum,
                                               int* __restrict__ bpre, int nb) {
  __shared__ int sh[128];
  int t = threadIdx.x;
  sh[t] = (t < nb) ? bsum[t] : 0;
  __syncthreads();
  for (int d = 1; d < 128; d <<= 1) {
    int v = (t >= d) ? sh[t - d] : 0;
    __syncthreads();
    sh[t] += v;
    __syncthreads();
  }
  if (t < nb) bpre[t] = (t == 0) ? 0 : sh[t - 1];
}

__global__ __launch_bounds__(1024) void k_scan2(const int* __restrict__ counts,
                                                const int* __restrict__ bpre,
                                                int* __restrict__ offs,
                                                int* __restrict__ cursor, int N) {
  __shared__ int sh[1024];
  int t = threadIdx.x;
  int i = blockIdx.x * 1024 + t;
  int v = (i < N) ? counts[i] : 0;
  sh[t] = v;
  __syncthreads();
  for (int d = 1; d < 1024; d <<= 1) {
    int u = (t >= d) ? sh[t - d] : 0;
    __syncthreads();
    sh[t] += u;
    __syncthreads();
  }
  if (i < N) {
    int excl = bpre[blockIdx.x] + sh[t] - v;
    offs[i] = excl;
    cursor[i] = excl;
    if (i == N - 1) offs[N] = excl + v;
  }
}

__global__ void k_scatter(const int* __restrict__ ei, int* __restrict__ cursor,
                          int* __restrict__ sorted, int E) {
  int i = blockIdx.x * 256 + threadIdx.x;
  if (i < E) {
    int pos = atomicAdd(&cursor[ei[E + i]], 1);
    sorted[pos] = i;
  }
}

// ---- prep: shuffle W (f32, [K=128][N=128]) into bf16 MFMA B-frag layout ---
// layout: uint4 index = ((mat*8+nt)*4+kt)*64 + lane ; 8 bf16 per entry.
// B-frag (16x16x32): n = nt*16+(lane&15), k = kt*32+(j>>2)*16+(lane>>4)*4+(j&3)
struct PrepArgs { const float* W[5]; };
__global__ void k_prep(PrepArgs pa, short* __restrict__ wf) {
  int tid = blockIdx.x * 256 + threadIdx.x;
  if (tid >= 5 * 8 * 4 * 64) return;
  int lane = tid & 63;
  int kt = (tid >> 6) & 3;
  int nt = (tid >> 8) & 7;
  int mat = tid >> 11;
  const float* W = pa.W[mat];
  int n = nt * 16 + (lane & 15);
  short v[8];
#pragma unroll
  for (int j = 0; j < 8; ++j) {
    int k = kt * 32 + ((j >> 2) * 16) + ((lane >> 4) * 4) + (j & 3);
    v[j] = f2bf(W[k * 128 + n]);
  }
  ((uint4*)wf)[tid] = *(uint4*)v;
}

// ---- node GEMMs (q,k,v bf16 out; skip f32 -> d_out) -----------------------
struct NodeArgs {
  const short* wf;
  const float* bias[4];
  void* outp[4];
};

__global__ __launch_bounds__(256, 1) void k_node(
    const float* __restrict__ x, const float* __restrict__ feats,
    NodeArgs na, int N) {
  const int w = blockIdx.y;               // 0=q 1=k 2=v 3=skip
  const int lane = threadIdx.x & 63;
  const int wv = threadIdx.x >> 6;

  bf16x8 bfrag[8][4];
  const uint4* wfp = (const uint4*)na.wf + (size_t)w * 2048;
#pragma unroll
  for (int nt = 0; nt < 8; ++nt)
#pragma unroll
    for (int kt = 0; kt < 4; ++kt)
      *(uint4*)&bfrag[nt][kt] = wfp[(nt * 4 + kt) * 64 + lane];

  float biasv[8];
#pragma unroll
  for (int nt = 0; nt < 8; ++nt) biasv[nt] = na.bias[w][nt * 16 + (lane & 15)];

  const int arow = lane & 15;
  const int k4 = (lane >> 4) * 4;
  const int ntiles = (N + 15) / 16;
  const int nwaves = gridDim.x * 4;
  for (int tile = blockIdx.x * 4 + wv; tile < ntiles; tile += nwaves) {
    int row = tile * 16 + arow;
    bool valid = row < N;
    const float* xr = x + (size_t)row * 64;
    const float* fr = feats + (size_t)row * 64;
    bf16x8 afrag[4];
#pragma unroll
    for (int kt = 0; kt < 4; ++kt) {
      const float* src = (kt < 2) ? xr : fr;
      int base = (kt & 1) * 32 + k4;
      float4 lo = valid ? *(const float4*)(src + base) : make_float4(0, 0, 0, 0);
      float4 hi = valid ? *(const float4*)(src + base + 16) : make_float4(0, 0, 0, 0);
      bf16x8 a;
      a[0] = f2bf(lo.x); a[1] = f2bf(lo.y); a[2] = f2bf(lo.z); a[3] = f2bf(lo.w);
      a[4] = f2bf(hi.x); a[5] = f2bf(hi.y); a[6] = f2bf(hi.z); a[7] = f2bf(hi.w);
      afrag[kt] = a;
    }
#pragma unroll
    for (int nt = 0; nt < 8; ++nt) {
      f32x4 acc = {0.f, 0.f, 0.f, 0.f};
#pragma unroll
      for (int kt = 0; kt < 4; ++kt)
        acc = __builtin_amdgcn_mfma_f32_16x16x32_bf16(afrag[kt], bfrag[nt][kt], acc, 0, 0, 0);
      int col = nt * 16 + (lane & 15);
#pragma unroll
      for (int reg = 0; reg < 4; ++reg) {
        int orow = tile * 16 + (lane >> 4) * 4 + reg;
        if (orow < N) {
          float vv = acc[reg] + biasv[nt];
          if (w < 3) ((short*)na.outp[w])[(size_t)orow * 128 + col] = f2bf(vv);
          else       ((float*)na.outp[3])[(size_t)orow * 128 + col] = vv;
        }
      }
    }
  }
}

// ---- edge kernel: e = edge_attr@We (MFMA) + alpha ------------------------
__global__ __launch_bounds__(256, 1) void k_edge2(
    const float* __restrict__ lu, const int* __restrict__ ei,
    const float* __restrict__ t, const float* __restrict__ msg,
    const float* __restrict__ tw, const float* __restrict__ tb,
    const short* __restrict__ wf, const short* __restrict__ qb,
    const short* __restrict__ kb, short* __restrict__ e_buf,
    float* __restrict__ alpha, int E) {
  const int lane = threadIdx.x & 63;
  const int wv = threadIdx.x >> 6;
  __shared__ short ea[4][2048];           // per-wave 16x128 bf16 transpose buf
  short* myea = ea[wv];

  bf16x8 bfrag[8][4];
  const uint4* wfp = (const uint4*)wf + (size_t)4 * 2048;   // mat 4 = We
#pragma unroll
  for (int nt = 0; nt < 8; ++nt)
#pragma unroll
    for (int kt = 0; kt < 4; ++kt)
      *(uint4*)&bfrag[nt][kt] = wfp[(nt * 4 + kt) * 64 + lane];

  const int k4 = (lane >> 4) * 4;
  // time-encoder weights for this lane's A-fragment slots (kt=0,1)
  float twv[16], tbv[16];
#pragma unroll
  for (int kt = 0; kt < 2; ++kt) {
    int base = kt * 32 + k4;
    *(float4*)&twv[kt * 8]     = *(const float4*)(tw + base);
    *(float4*)&twv[kt * 8 + 4] = *(const float4*)(tw + base + 16);
    *(float4*)&tbv[kt * 8]     = *(const float4*)(tb + base);
    *(float4*)&tbv[kt * 8 + 4] = *(const float4*)(tb + base + 16);
  }

  const int ntiles = (E + 15) / 16;
  const int nwaves = gridDim.x * 4;
  for (int tile = blockIdx.x * 4 + wv; tile < ntiles; tile += nwaves) {
    const int e0 = tile * 16;
    int srcv = 0, dstv = 0;
    float relt = 0.f;
    if (lane < 16 && e0 + lane < E) {
      srcv = ei[e0 + lane];
      dstv = ei[E + e0 + lane];
      relt = lu[srcv] - t[e0 + lane];
    }
    const int r = lane & 15;
    float my_relt = __shfl(relt, r);
    bool rvalid = (e0 + r) < E;

    bf16x8 afrag[4];
#pragma unroll
    for (int kt = 0; kt < 2; ++kt) {
      bf16x8 a;
#pragma unroll
      for (int j = 0; j < 8; ++j)
        a[j] = f2bf(__cosf(my_relt * twv[kt * 8 + j] + tbv[kt * 8 + j]));
      afrag[kt] = a;
    }
    const float* mr = msg + (size_t)(e0 + r) * 64;
#pragma unroll
    for (int kt = 2; kt < 4; ++kt) {
      int base = (kt - 2) * 32 + k4;
      float4 lo = rvalid ? *(const float4*)(mr + base) : make_float4(0, 0, 0, 0);
      float4 hi = rvalid ? *(const float4*)(mr + base + 16) : make_float4(0, 0, 0, 0);
      bf16x8 a;
      a[0] = f2bf(lo.x); a[1] = f2bf(lo.y); a[2] = f2bf(lo.z); a[3] = f2bf(lo.w);
      a[4] = f2bf(hi.x); a[5] = f2bf(hi.y); a[6] = f2bf(hi.z); a[7] = f2bf(hi.w);
      afrag[kt] = a;
    }

#pragma unroll
    for (int nt = 0; nt < 8; ++nt) {
      f32x4 acc = {0.f, 0.f, 0.f, 0.f};
#pragma unroll
      for (int kt = 0; kt < 4; ++kt)
        acc = __builtin_amdgcn_mfma_f32_16x16x32_bf16(afrag[kt], bfrag[nt][kt], acc, 0, 0, 0);
      int col = nt * 16 + (lane & 15);
#pragma unroll
      for (int reg = 0; reg < 4; ++reg) {
        int er = (lane >> 4) * 4 + reg;
        short bv = f2bf(acc[reg]);
        if (e0 + er < E) e_buf[(size_t)(e0 + er) * 128 + col] = bv;
        int off = er * 256 + (((nt * 32) + ((lane & 15) * 2)) ^ ((er & 7) << 4));
        *(short*)((char*)myea + off) = bv;
      }
    }

    // alpha: lane -> edge r2=lane&15, col-block cb=lane>>4 (32 cols = 2 heads)
    const int r2 = lane & 15;
    const int cb = lane >> 4;
    int src2 = __shfl(srcv, r2);
    int dst2 = __shfl(dstv, r2);
    const short* qrow = qb + (size_t)dst2 * 128 + cb * 32;
    const short* krow = kb + (size_t)src2 * 128 + cb * 32;
    float h0 = 0.f, h1 = 0.f;
#pragma unroll
    for (int i = 0; i < 4; ++i) {
      uint4 qv = *(const uint4*)(qrow + i * 8);
      uint4 kv = *(const uint4*)(krow + i * 8);
      uint4 ev = *(const uint4*)((char*)myea + r2 * 256 +
                                 (((cb * 64) + i * 16) ^ ((r2 & 7) << 4)));
      float sum = 0.f;
#pragma unroll
      for (int c = 0; c < 8; ++c) {
        float qf = bf2f(((short*)&qv)[c]);
        float kf = bf2f(((short*)&kv)[c]);
        float ef = bf2f(((short*)&ev)[c]);
        sum = fmaf(qf, kf + ef, sum);
      }
      if (i < 2) h0 += sum; else h1 += sum;
    }
    if ((e0 + r2) < E) {
      float* ap = alpha + (size_t)(e0 + r2) * 8 + cb * 2;
      ap[0] = h0 * 0.25f;
      ap[1] = h1 * 0.25f;
    }
  }
}

// ---- per-dst aggregation: one wave per node -------------------------------
__global__ __launch_bounds__(256) void k_agg(
    const int* __restrict__ ei, const int* __restrict__ offs,
    const int* __restrict__ sorted, const float* __restrict__ alpha,
    const short* __restrict__ e_buf, const short* __restrict__ vb,
    float* __restrict__ out, int N) {
  const int wave = threadIdx.x >> 6;
  const int lane = threadIdx.x & 63;
  const int n = blockIdx.x * 4 + wave;
  if (n >= N) return;
  const int off = offs[n], end = offs[n + 1];
  const int h1 = lane >> 4;
  const int h2 = h1 + 4;
  const int o1 = lane, o2 = lane + 64;
  float acc1 = 0.f, acc2 = 0.f;
  if (end > off) {
    float m1 = -1e30f, m2 = -1e30f;
    for (int i = off; i < end; ++i) {
      int eid = sorted[i];
      m1 = fmaxf(m1, alpha[(size_t)eid * 8 + h1]);
      m2 = fmaxf(m2, alpha[(size_t)eid * 8 + h2]);
    }
    float s1 = 0.f, s2 = 0.f;
    for (int i = off; i < end; ++i) {
      int eid = sorted[i];
      s1 += __expf(alpha[(size_t)eid * 8 + h1] - m1);
      s2 += __expf(alpha[(size_t)eid * 8 + h2] - m2);
    }
    const float r1 = 1.f / (s1 + 1e-16f);
    const float r2 = 1.f / (s2 + 1e-16f);
    for (int i = off; i < end; ++i) {
      int eid = sorted[i];
      int src = ei[eid];
      float a1 = __expf(alpha[(size_t)eid * 8 + h1] - m1) * r1;
      float a2 = __expf(alpha[(size_t)eid * 8 + h2] - m2) * r2;
      acc1 += (bf2f(vb[(size_t)src * 128 + o1]) + bf2f(e_buf[(size_t)eid * 128 + o1])) * a1;
      acc2 += (bf2f(vb[(size_t)src * 128 + o2]) + bf2f(e_buf[(size_t)eid * 128 + o2])) * a2;
    }
  }
  out[(size_t)n * 128 + o1] += acc1;
  out[(size_t)n * 128 + o2] += acc2;
}

extern "C" void kernel_launch(void* const* d_in, const int* in_sizes, int n_in,
                              void* d_out, int out_size, void* d_ws, size_t ws_size,
                              hipStream_t stream) {
  const float* feats = (const float*)d_in[0];
  const float* x     = (const float*)d_in[1];
  const float* lu    = (const float*)d_in[2];
  const int*   ei    = (const int*)d_in[3];
  const float* t     = (const float*)d_in[4];
  const float* msg   = (const float*)d_in[5];
  const float* tw    = (const float*)d_in[6];
  const float* tb    = (const float*)d_in[7];
  const float* Wq    = (const float*)d_in[8];
  const float* bq    = (const float*)d_in[9];
  const float* Wk    = (const float*)d_in[10];
  const float* bk    = (const float*)d_in[11];
  const float* Wv    = (const float*)d_in[12];
  const float* bv    = (const float*)d_in[13];
  const float* We    = (const float*)d_in[14];
  const float* Wskip = (const float*)d_in[15];
  const float* bskip = (const float*)d_in[16];
  float* out = (float*)d_out;
  const int N = in_sizes[2];
  const int E = in_sizes[4];

  char* ws = (char*)d_ws;
  short* wfrag = (short*)ws; ws += 5 * 2048 * 16;            // 160 KB, frag layout
  short* qb    = (short*)ws; ws += (size_t)N * 128 * 2;
  short* kbuf  = (short*)ws; ws += (size_t)N * 128 * 2;
  short* vbuf  = (short*)ws; ws += (size_t)N * 128 * 2;
  short* e_buf = (short*)ws; ws += (size_t)E * 128 * 2;
  float* alpha = (float*)ws; ws += (size_t)E * 8 * 4;
  int* counts  = (int*)ws;   ws += (size_t)(N + 1) * 4;
  int* offs    = (int*)ws;   ws += (size_t)(N + 1) * 4;
  int* cursor  = (int*)ws;   ws += (size_t)N * 4;
  int* sorted  = (int*)ws;   ws += (size_t)E * 4;
  int* bsum    = (int*)ws;   ws += 128 * 4;
  int* bpre    = (int*)ws;   ws += 128 * 4;

  const int nb = (N + 1023) / 1024;

  hipMemsetAsync(counts, 0, (size_t)(N + 1) * 4, stream);
  k_hist<<<(E + 255) / 256, 256, 0, stream>>>(ei, counts, E);
  k_bsum<<<nb, 1024, 0, stream>>>(counts, bsum, N);
  k_bscan<<<1, 128, 0, stream>>>(bsum, bpre, nb);
  k_scan2<<<nb, 1024, 0, stream>>>(counts, bpre, offs, cursor, N);
  k_scatter<<<(E + 255) / 256, 256, 0, stream>>>(ei, cursor, sorted, E);

  PrepArgs pa;
  pa.W[0] = Wq; pa.W[1] = Wk; pa.W[2] = Wv; pa.W[3] = Wskip; pa.W[4] = We;
  k_prep<<<40, 256, 0, stream>>>(pa, wfrag);

  NodeArgs na;
  na.wf = wfrag;
  na.bias[0] = bq; na.bias[1] = bk; na.bias[2] = bv; na.bias[3] = bskip;
  na.outp[0] = qb; na.outp[1] = kbuf; na.outp[2] = vbuf; na.outp[3] = out;
  dim3 gnode(128, 4);
  k_node<<<gnode, 256, 0, stream>>>(x, feats, na, N);

  k_edge2<<<1024, 256, 0, stream>>>(lu, ei, t, msg, tw, tb, wfrag,
                                    qb, kbuf, e_buf, alpha, E);
  k_agg<<<(N + 3) / 4, 256, 0, stream>>>(ei, offs, sorted, alpha, e_buf, vbuf,
                                         out, N);
}

// Round 3
// 407.179 us; speedup vs baseline: 3.5195x; 1.2444x over previous
//
#include <hip/hip_runtime.h>
#include <math.h>

// ---------------------------------------------------------------------------
// TGN GraphAttentionEmbedding, MFMA bf16 version.
//   h = [x, feats]  (N,128);  q/k/v/skip = h@W*+b*  (MFMA, bf16 out except skip)
//   edge_attr = [cos((lu[src]-t)*tw+tb), msg]; e = edge_attr@We (MFMA, bf16)
//   alpha = sum_head(q[dst]*(k[src]+e))/4 ; segment softmax over dst; aggregate
// ---------------------------------------------------------------------------

typedef __attribute__((ext_vector_type(8))) short bf16x8;
typedef __attribute__((ext_vector_type(4))) float f32x4;

__device__ inline short f2bf(float f) {
  unsigned u = __float_as_uint(f);
  u += 0x7fff + ((u >> 16) & 1);     // round-to-nearest-even
  return (short)(u >> 16);
}
__device__ inline float bf2f(short s) {
  return __uint_as_float(((unsigned)(unsigned short)s) << 16);
}
__device__ inline float sel8(float v0, float v1, float v2, float v3,
                             float v4, float v5, float v6, float v7, int h) {
  float a = (h & 1) ? v1 : v0;
  float b = (h & 1) ? v3 : v2;
  float c = (h & 1) ? v5 : v4;
  float d = (h & 1) ? v7 : v6;
  float e = (h & 2) ? b : a;
  float f = (h & 2) ? d : c;
  return (h & 4) ? f : e;
}

// ---- sort edges by dst ----------------------------------------------------
__global__ void k_hist(const int* __restrict__ ei, int* __restrict__ counts, int E) {
  int i = blockIdx.x * 256 + threadIdx.x;
  if (i < E) atomicAdd(&counts[ei[E + i]], 1);
}

__global__ __launch_bounds__(1024) void k_bsum(const int* __restrict__ counts,
                                               int* __restrict__ bsum, int N) {
  int i = blockIdx.x * 1024 + threadIdx.x;
  int v = (i < N) ? counts[i] : 0;
  for (int d = 32; d; d >>= 1) v += __shfl_down(v, d);
  __shared__ int ws_[16];
  int lane = threadIdx.x & 63, wv = threadIdx.x >> 6;
  if (lane == 0) ws_[wv] = v;
  __syncthreads();
  if (threadIdx.x == 0) {
    int s = 0;
    for (int j = 0; j < 16; ++j) s += ws_[j];
    bsum[blockIdx.x] = s;
  }
}

__global__ __launch_bounds__(128) void k_bscan(const int* __restrict__ bsum,
                                               int* __restrict__ bpre, int nb) {
  __shared__ int sh[128];
  int t = threadIdx.x;
  sh[t] = (t < nb) ? bsum[t] : 0;
  __syncthreads();
  for (int d = 1; d < 128; d <<= 1) {
    int v = (t >= d) ? sh[t - d] : 0;
    __syncthreads();
    sh[t] += v;
    __syncthreads();
  }
  if (t < nb) bpre[t] = (t == 0) ? 0 : sh[t - 1];
}

__global__ __launch_bounds__(1024) void k_scan2(const int* __restrict__ counts,
                                                const int* __restrict__ bpre,
                                                int* __restrict__ offs,
                                                int* __restrict__ cursor, int N) {
  __shared__ int sh[1024];
  int t = threadIdx.x;
  int i = blockIdx.x * 1024 + t;
  int v = (i < N) ? counts[i] : 0;
  sh[t] = v;
  __syncthreads();
  for (int d = 1; d < 1024; d <<= 1) {
    int u = (t >= d) ? sh[t - d] : 0;
    __syncthreads();
    sh[t] += u;
    __syncthreads();
  }
  if (i < N) {
    int excl = bpre[blockIdx.x] + sh[t] - v;
    offs[i] = excl;
    cursor[i] = excl;
    if (i == N - 1) offs[N] = excl + v;
  }
}

__global__ void k_scatter(const int* __restrict__ ei, int* __restrict__ cursor,
                          int* __restrict__ sorted, int E) {
  int i = blockIdx.x * 256 + threadIdx.x;
  if (i < E) {
    int pos = atomicAdd(&cursor[ei[E + i]], 1);
    sorted[pos] = i;
  }
}

// ---- prep: shuffle W (f32, [K=128][N=128]) into bf16 MFMA B-frag layout ---
struct PrepArgs { const float* W[5]; };
__global__ void k_prep(PrepArgs pa, short* __restrict__ wf) {
  int tid = blockIdx.x * 256 + threadIdx.x;
  if (tid >= 5 * 8 * 4 * 64) return;
  int lane = tid & 63;
  int kt = (tid >> 6) & 3;
  int nt = (tid >> 8) & 7;
  int mat = tid >> 11;
  const float* W = pa.W[mat];
  int n = nt * 16 + (lane & 15);
  short v[8];
#pragma unroll
  for (int j = 0; j < 8; ++j) {
    int k = kt * 32 + ((j >> 2) * 16) + ((lane >> 4) * 4) + (j & 3);
    v[j] = f2bf(W[k * 128 + n]);
  }
  ((uint4*)wf)[tid] = *(uint4*)v;
}

// ---- node GEMMs (q,k,v bf16 out; skip f32 -> d_out) -----------------------
struct NodeArgs {
  const short* wf;
  const float* bias[4];
  void* outp[4];
};

__global__ __launch_bounds__(256, 1) void k_node(
    const float* __restrict__ x, const float* __restrict__ feats,
    NodeArgs na, int N) {
  const int w = blockIdx.y;               // 0=q 1=k 2=v 3=skip
  const int lane = threadIdx.x & 63;
  const int wv = threadIdx.x >> 6;

  bf16x8 bfrag[8][4];
  const uint4* wfp = (const uint4*)na.wf + (size_t)w * 2048;
#pragma unroll
  for (int nt = 0; nt < 8; ++nt)
#pragma unroll
    for (int kt = 0; kt < 4; ++kt)
      *(uint4*)&bfrag[nt][kt] = wfp[(nt * 4 + kt) * 64 + lane];

  float biasv[8];
#pragma unroll
  for (int nt = 0; nt < 8; ++nt) biasv[nt] = na.bias[w][nt * 16 + (lane & 15)];

  const int arow = lane & 15;
  const int k4 = (lane >> 4) * 4;
  const int ntiles = (N + 15) / 16;
  const int nwaves = gridDim.x * 4;
  for (int tile = blockIdx.x * 4 + wv; tile < ntiles; tile += nwaves) {
    int row = tile * 16 + arow;
    bool valid = row < N;
    const float* xr = x + (size_t)row * 64;
    const float* fr = feats + (size_t)row * 64;
    bf16x8 afrag[4];
#pragma unroll
    for (int kt = 0; kt < 4; ++kt) {
      const float* src = (kt < 2) ? xr : fr;
      int base = (kt & 1) * 32 + k4;
      float4 lo = valid ? *(const float4*)(src + base) : make_float4(0, 0, 0, 0);
      float4 hi = valid ? *(const float4*)(src + base + 16) : make_float4(0, 0, 0, 0);
      bf16x8 a;
      a[0] = f2bf(lo.x); a[1] = f2bf(lo.y); a[2] = f2bf(lo.z); a[3] = f2bf(lo.w);
      a[4] = f2bf(hi.x); a[5] = f2bf(hi.y); a[6] = f2bf(hi.z); a[7] = f2bf(hi.w);
      afrag[kt] = a;
    }
#pragma unroll
    for (int nt = 0; nt < 8; ++nt) {
      f32x4 acc = {0.f, 0.f, 0.f, 0.f};
#pragma unroll
      for (int kt = 0; kt < 4; ++kt)
        acc = __builtin_amdgcn_mfma_f32_16x16x32_bf16(afrag[kt], bfrag[nt][kt], acc, 0, 0, 0);
      int col = nt * 16 + (lane & 15);
#pragma unroll
      for (int reg = 0; reg < 4; ++reg) {
        int orow = tile * 16 + (lane >> 4) * 4 + reg;
        if (orow < N) {
          float vv = acc[reg] + biasv[nt];
          if (w < 3) ((short*)na.outp[w])[(size_t)orow * 128 + col] = f2bf(vv);
          else       ((float*)na.outp[3])[(size_t)orow * 128 + col] = vv;
        }
      }
    }
  }
}

// ---- edge kernel: e = edge_attr@We (MFMA) + alpha ------------------------
__global__ __launch_bounds__(256, 1) void k_edge2(
    const float* __restrict__ lu, const int* __restrict__ ei,
    const float* __restrict__ t, const float* __restrict__ msg,
    const float* __restrict__ tw, const float* __restrict__ tb,
    const short* __restrict__ wf, const short* __restrict__ qb,
    const short* __restrict__ kb, short* __restrict__ e_buf,
    float* __restrict__ alpha, int E) {
  const int lane = threadIdx.x & 63;
  const int wv = threadIdx.x >> 6;
  __shared__ short ea[4][2048];           // per-wave 16x128 bf16 transpose buf
  short* myea = ea[wv];

  bf16x8 bfrag[8][4];
  const uint4* wfp = (const uint4*)wf + (size_t)4 * 2048;   // mat 4 = We
#pragma unroll
  for (int nt = 0; nt < 8; ++nt)
#pragma unroll
    for (int kt = 0; kt < 4; ++kt)
      *(uint4*)&bfrag[nt][kt] = wfp[(nt * 4 + kt) * 64 + lane];

  const int k4 = (lane >> 4) * 4;
  float twv[16], tbv[16];
#pragma unroll
  for (int kt = 0; kt < 2; ++kt) {
    int base = kt * 32 + k4;
    *(float4*)&twv[kt * 8]     = *(const float4*)(tw + base);
    *(float4*)&twv[kt * 8 + 4] = *(const float4*)(tw + base + 16);
    *(float4*)&tbv[kt * 8]     = *(const float4*)(tb + base);
    *(float4*)&tbv[kt * 8 + 4] = *(const float4*)(tb + base + 16);
  }

  const int ntiles = (E + 15) / 16;
  const int nwaves = gridDim.x * 4;
  for (int tile = blockIdx.x * 4 + wv; tile < ntiles; tile += nwaves) {
    const int e0 = tile * 16;
    int srcv = 0, dstv = 0;
    float relt = 0.f;
    if (lane < 16 && e0 + lane < E) {
      srcv = ei[e0 + lane];
      dstv = ei[E + e0 + lane];
      relt = lu[srcv] - t[e0 + lane];
    }
    const int r = lane & 15;
    float my_relt = __shfl(relt, r);
    bool rvalid = (e0 + r) < E;

    bf16x8 afrag[4];
#pragma unroll
    for (int kt = 0; kt < 2; ++kt) {
      bf16x8 a;
#pragma unroll
      for (int j = 0; j < 8; ++j)
        a[j] = f2bf(__cosf(my_relt * twv[kt * 8 + j] + tbv[kt * 8 + j]));
      afrag[kt] = a;
    }
    const float* mr = msg + (size_t)(e0 + r) * 64;
#pragma unroll
    for (int kt = 2; kt < 4; ++kt) {
      int base = (kt - 2) * 32 + k4;
      float4 lo = rvalid ? *(const float4*)(mr + base) : make_float4(0, 0, 0, 0);
      float4 hi = rvalid ? *(const float4*)(mr + base + 16) : make_float4(0, 0, 0, 0);
      bf16x8 a;
      a[0] = f2bf(lo.x); a[1] = f2bf(lo.y); a[2] = f2bf(lo.z); a[3] = f2bf(lo.w);
      a[4] = f2bf(hi.x); a[5] = f2bf(hi.y); a[6] = f2bf(hi.z); a[7] = f2bf(hi.w);
      afrag[kt] = a;
    }

#pragma unroll
    for (int nt = 0; nt < 8; ++nt) {
      f32x4 acc = {0.f, 0.f, 0.f, 0.f};
#pragma unroll
      for (int kt = 0; kt < 4; ++kt)
        acc = __builtin_amdgcn_mfma_f32_16x16x32_bf16(afrag[kt], bfrag[nt][kt], acc, 0, 0, 0);
      int col = nt * 16 + (lane & 15);
#pragma unroll
      for (int reg = 0; reg < 4; ++reg) {
        int er = (lane >> 4) * 4 + reg;
        short bv = f2bf(acc[reg]);
        if (e0 + er < E) e_buf[(size_t)(e0 + er) * 128 + col] = bv;
        int off = er * 256 + (((nt * 32) + ((lane & 15) * 2)) ^ ((er & 7) << 4));
        *(short*)((char*)myea + off) = bv;
      }
    }

    // alpha: lane -> edge r2=lane&15, col-block cb=lane>>4 (32 cols = 2 heads)
    const int r2 = lane & 15;
    const int cb = lane >> 4;
    int src2 = __shfl(srcv, r2);
    int dst2 = __shfl(dstv, r2);
    const short* qrow = qb + (size_t)dst2 * 128 + cb * 32;
    const short* krow = kb + (size_t)src2 * 128 + cb * 32;
    float h0 = 0.f, h1 = 0.f;
#pragma unroll
    for (int i = 0; i < 4; ++i) {
      uint4 qv = *(const uint4*)(qrow + i * 8);
      uint4 kv = *(const uint4*)(krow + i * 8);
      uint4 ev = *(const uint4*)((char*)myea + r2 * 256 +
                                 (((cb * 64) + i * 16) ^ ((r2 & 7) << 4)));
      float sum = 0.f;
#pragma unroll
      for (int c = 0; c < 8; ++c) {
        float qf = bf2f(((short*)&qv)[c]);
        float kf = bf2f(((short*)&kv)[c]);
        float ef = bf2f(((short*)&ev)[c]);
        sum = fmaf(qf, kf + ef, sum);
      }
      if (i < 2) h0 += sum; else h1 += sum;
    }
    if ((e0 + r2) < E) {
      float2 av = make_float2(h0 * 0.25f, h1 * 0.25f);
      *(float2*)(alpha + (size_t)(e0 + r2) * 8 + cb * 2) = av;
    }
  }
}

// ---- per-dst aggregation: one wave per node, single pass ------------------
// lane i owns edge off+i (64-edge chunks, online rescale across chunks).
// lane handles output channel pair (2*lane, 2*lane+1) -> one head h=lane>>3.
__global__ __launch_bounds__(256) void k_agg(
    const int* __restrict__ ei, const int* __restrict__ offs,
    const int* __restrict__ sorted, const float* __restrict__ alpha,
    const short* __restrict__ e_buf, const short* __restrict__ vb,
    float* __restrict__ out, int N) {
  __shared__ int   lds_eo[4][64];
  __shared__ int   lds_vo[4][64];
  __shared__ float lds_ex[4][64][8];
  const int wave = threadIdx.x >> 6;
  const int lane = threadIdx.x & 63;
  const int n = blockIdx.x * 4 + wave;
  if (n >= N) return;
  const int off = offs[n], end = offs[n + 1];
  if (end == off) return;                 // out keeps skip value
  const int h = lane >> 3;
  const int c2 = lane * 2;

  float m[8], s[8];
#pragma unroll
  for (int k = 0; k < 8; ++k) { m[k] = -1e30f; s[k] = 0.f; }
  float acc0 = 0.f, acc1 = 0.f;

  for (int c0 = off; c0 < end; c0 += 64) {
    const int cnt = min(64, end - c0);
    const bool act = lane < cnt;
    float a[8];
    if (act) {
      int eid = sorted[c0 + lane];
      int src = ei[eid];
      lds_eo[wave][lane] = eid * 128;
      lds_vo[wave][lane] = src * 128;
      float4 lo = *(const float4*)(alpha + (size_t)eid * 8);
      float4 hi = *(const float4*)(alpha + (size_t)eid * 8 + 4);
      a[0] = lo.x; a[1] = lo.y; a[2] = lo.z; a[3] = lo.w;
      a[4] = hi.x; a[5] = hi.y; a[6] = hi.z; a[7] = hi.w;
    } else {
#pragma unroll
      for (int k = 0; k < 8; ++k) a[k] = -1e30f;
    }
    // per-head chunk max (64-lane butterfly), combine with running max
    float mn[8], sc[8];
#pragma unroll
    for (int k = 0; k < 8; ++k) {
      float v = a[k];
#pragma unroll
      for (int d = 1; d < 64; d <<= 1) v = fmaxf(v, __shfl_xor(v, d));
      mn[k] = fmaxf(m[k], v);
      sc[k] = __expf(m[k] - mn[k]);       // 0 on first chunk
      float ex = act ? __expf(a[k] - mn[k]) : 0.f;
      lds_ex[wave][lane][k] = ex;
      float ss = ex;
#pragma unroll
      for (int d = 1; d < 64; d <<= 1) ss += __shfl_xor(ss, d);
      s[k] = s[k] * sc[k] + ss;
      m[k] = mn[k];
    }
    // rescale running accumulator (head h for this lane's channels)
    float schn = sel8(sc[0], sc[1], sc[2], sc[3], sc[4], sc[5], sc[6], sc[7], h);
    acc0 *= schn; acc1 *= schn;
    // aggregate this chunk: broadcast per-edge row offsets + weight from LDS
    for (int j = 0; j < cnt; ++j) {
      int eo = lds_eo[wave][j];
      int vo = lds_vo[wave][j];
      float w = lds_ex[wave][j][h];
      unsigned ev = *(const unsigned*)(e_buf + (size_t)eo + c2);
      unsigned vv = *(const unsigned*)(vb + (size_t)vo + c2);
      float e0 = bf2f((short)(ev & 0xffff)), e1 = bf2f((short)(ev >> 16));
      float v0 = bf2f((short)(vv & 0xffff)), v1 = bf2f((short)(vv >> 16));
      acc0 = fmaf(v0 + e0, w, acc0);
      acc1 = fmaf(v1 + e1, w, acc1);
    }
  }
  float sh = sel8(s[0], s[1], s[2], s[3], s[4], s[5], s[6], s[7], h);
  float r = 1.f / (sh + 1e-16f);
  float2 o = *(float2*)(out + (size_t)n * 128 + c2);
  o.x += acc0 * r;
  o.y += acc1 * r;
  *(float2*)(out + (size_t)n * 128 + c2) = o;
}

extern "C" void kernel_launch(void* const* d_in, const int* in_sizes, int n_in,
                              void* d_out, int out_size, void* d_ws, size_t ws_size,
                              hipStream_t stream) {
  const float* feats = (const float*)d_in[0];
  const float* x     = (const float*)d_in[1];
  const float* lu    = (const float*)d_in[2];
  const int*   ei    = (const int*)d_in[3];
  const float* t     = (const float*)d_in[4];
  const float* msg   = (const float*)d_in[5];
  const float* tw    = (const float*)d_in[6];
  const float* tb    = (const float*)d_in[7];
  const float* Wq    = (const float*)d_in[8];
  const float* bq    = (const float*)d_in[9];
  const float* Wk    = (const float*)d_in[10];
  const float* bk    = (const float*)d_in[11];
  const float* Wv    = (const float*)d_in[12];
  const float* bv    = (const float*)d_in[13];
  const float* We    = (const float*)d_in[14];
  const float* Wskip = (const float*)d_in[15];
  const float* bskip = (const float*)d_in[16];
  float* out = (float*)d_out;
  const int N = in_sizes[2];
  const int E = in_sizes[4];

  char* ws = (char*)d_ws;
  short* wfrag = (short*)ws; ws += 5 * 2048 * 16;            // 160 KB
  short* qb    = (short*)ws; ws += (size_t)N * 128 * 2;
  short* kbuf  = (short*)ws; ws += (size_t)N * 128 * 2;
  short* vbuf  = (short*)ws; ws += (size_t)N * 128 * 2;
  short* e_buf = (short*)ws; ws += (size_t)E * 128 * 2;
  float* alpha = (float*)ws; ws += (size_t)E * 8 * 4;
  int* counts  = (int*)ws;   ws += (size_t)(N + 1) * 4;
  int* offs    = (int*)ws;   ws += (size_t)(N + 1) * 4;
  int* cursor  = (int*)ws;   ws += (size_t)N * 4;
  int* sorted  = (int*)ws;   ws += (size_t)E * 4;
  int* bsum    = (int*)ws;   ws += 128 * 4;
  int* bpre    = (int*)ws;   ws += 128 * 4;

  const int nb = (N + 1023) / 1024;

  hipMemsetAsync(counts, 0, (size_t)(N + 1) * 4, stream);
  k_hist<<<(E + 255) / 256, 256, 0, stream>>>(ei, counts, E);
  k_bsum<<<nb, 1024, 0, stream>>>(counts, bsum, N);
  k_bscan<<<1, 128, 0, stream>>>(bsum, bpre, nb);
  k_scan2<<<nb, 1024, 0, stream>>>(counts, bpre, offs, cursor, N);
  k_scatter<<<(E + 255) / 256, 256, 0, stream>>>(ei, cursor, sorted, E);

  PrepArgs pa;
  pa.W[0] = Wq; pa.W[1] = Wk; pa.W[2] = Wv; pa.W[3] = Wskip; pa.W[4] = We;
  k_prep<<<40, 256, 0, stream>>>(pa, wfrag);

  NodeArgs na;
  na.wf = wfrag;
  na.bias[0] = bq; na.bias[1] = bk; na.bias[2] = bv; na.bias[3] = bskip;
  na.outp[0] = qb; na.outp[1] = kbuf; na.outp[2] = vbuf; na.outp[3] = out;
  dim3 gnode(128, 4);
  k_node<<<gnode, 256, 0, stream>>>(x, feats, na, N);

  k_edge2<<<1024, 256, 0, stream>>>(lu, ei, t, msg, tw, tb, wfrag,
                                    qb, kbuf, e_buf, alpha, E);
  k_agg<<<(N + 3) / 4, 256, 0, stream>>>(ei, offs, sorted, alpha, e_buf, vbuf,
                                         out, N);
}

// Round 4
// 355.323 us; speedup vs baseline: 4.0332x; 1.1459x over previous
//
#include <hip/hip_runtime.h>
#include <math.h>

// ---------------------------------------------------------------------------
// TGN GraphAttentionEmbedding, MFMA bf16, dst-sorted dataflow:
//   sort edges by dst (hist/scan/scatter) -> sorted[], src_s[]
//   k_node : h=[x,feats]; q/k/v (bf16) + skip (f32->out), 4 GEMMs fused
//   k_egemm: e[sorted_pos] = [cos((lu[src]-t)tw+tb), msg] @ We   (pure GEMM)
//   k_agg  : per dst node, fused online-softmax attention aggregate
// ---------------------------------------------------------------------------

typedef __attribute__((ext_vector_type(8))) short bf16x8;
typedef __attribute__((ext_vector_type(4))) float f32x4;

__device__ inline short f2bf(float f) {
  unsigned u = __float_as_uint(f);
  u += 0x7fff + ((u >> 16) & 1);     // round-to-nearest-even
  return (short)(u >> 16);
}
__device__ inline float bf2f(short s) {
  return __uint_as_float(((unsigned)(unsigned short)s) << 16);
}

// ---- sort edges by dst ----------------------------------------------------
__global__ void k_hist(const int* __restrict__ ei, int* __restrict__ counts, int E) {
  int i = blockIdx.x * 256 + threadIdx.x;
  if (i < E) atomicAdd(&counts[ei[E + i]], 1);
}

__global__ __launch_bounds__(1024) void k_bsum(const int* __restrict__ counts,
                                               int* __restrict__ bsum, int N) {
  int i = blockIdx.x * 1024 + threadIdx.x;
  int v = (i < N) ? counts[i] : 0;
  for (int d = 32; d; d >>= 1) v += __shfl_down(v, d);
  __shared__ int ws_[16];
  int lane = threadIdx.x & 63, wv = threadIdx.x >> 6;
  if (lane == 0) ws_[wv] = v;
  __syncthreads();
  if (threadIdx.x == 0) {
    int s = 0;
    for (int j = 0; j < 16; ++j) s += ws_[j];
    bsum[blockIdx.x] = s;
  }
}

__global__ __launch_bounds__(128) void k_bscan(const int* __restrict__ bsum,
                                               int* __restrict__ bpre, int nb) {
  __shared__ int sh[128];
  int t = threadIdx.x;
  sh[t] = (t < nb) ? bsum[t] : 0;
  __syncthreads();
  for (int d = 1; d < 128; d <<= 1) {
    int v = (t >= d) ? sh[t - d] : 0;
    __syncthreads();
    sh[t] += v;
    __syncthreads();
  }
  if (t < nb) bpre[t] = (t == 0) ? 0 : sh[t - 1];
}

__global__ __launch_bounds__(1024) void k_scan2(const int* __restrict__ counts,
                                                const int* __restrict__ bpre,
                                                int* __restrict__ offs,
                                                int* __restrict__ cursor, int N) {
  __shared__ int sh[1024];
  int t = threadIdx.x;
  int i = blockIdx.x * 1024 + t;
  int v = (i < N) ? counts[i] : 0;
  sh[t] = v;
  __syncthreads();
  for (int d = 1; d < 1024; d <<= 1) {
    int u = (t >= d) ? sh[t - d] : 0;
    __syncthreads();
    sh[t] += u;
    __syncthreads();
  }
  if (i < N) {
    int excl = bpre[blockIdx.x] + sh[t] - v;
    offs[i] = excl;
    cursor[i] = excl;
    if (i == N - 1) offs[N] = excl + v;
  }
}

__global__ void k_scatter(const int* __restrict__ ei, int* __restrict__ cursor,
                          int* __restrict__ sorted, int* __restrict__ src_s, int E) {
  int i = blockIdx.x * 256 + threadIdx.x;
  if (i < E) {
    int pos = atomicAdd(&cursor[ei[E + i]], 1);
    sorted[pos] = i;
    src_s[pos] = ei[i];
  }
}

// ---- prep: shuffle W (f32, [K=128][N=128]) into bf16 MFMA B-frag layout ---
struct PrepArgs { const float* W[5]; };
__global__ void k_prep(PrepArgs pa, short* __restrict__ wf) {
  int tid = blockIdx.x * 256 + threadIdx.x;
  if (tid >= 5 * 8 * 4 * 64) return;
  int lane = tid & 63;
  int kt = (tid >> 6) & 3;
  int nt = (tid >> 8) & 7;
  int mat = tid >> 11;
  const float* W = pa.W[mat];
  int n = nt * 16 + (lane & 15);
  short v[8];
#pragma unroll
  for (int j = 0; j < 8; ++j) {
    int k = kt * 32 + ((j >> 2) * 16) + ((lane >> 4) * 4) + (j & 3);
    v[j] = f2bf(W[k * 128 + n]);
  }
  ((uint4*)wf)[tid] = *(uint4*)v;
}

// ---- node GEMMs, all 4 mats in one kernel (A-frag reused) -----------------
struct NodeArgs {
  const short* wf;
  const float* bias[4];
  void* outp[4];
};

__global__ __launch_bounds__(256, 1) void k_node(
    const float* __restrict__ x, const float* __restrict__ feats,
    NodeArgs na, int N) {
  const int lane = threadIdx.x & 63;
  const int wv = threadIdx.x >> 6;
  const int arow = lane & 15;
  const int k4 = (lane >> 4) * 4;
  const int ntiles = (N + 15) / 16;
  const int nwaves = gridDim.x * 4;
  for (int tile = blockIdx.x * 4 + wv; tile < ntiles; tile += nwaves) {
    int row = tile * 16 + arow;
    bool valid = row < N;
    const float* xr = x + (size_t)row * 64;
    const float* fr = feats + (size_t)row * 64;
    bf16x8 afrag[4];
#pragma unroll
    for (int kt = 0; kt < 4; ++kt) {
      const float* src = (kt < 2) ? xr : fr;
      int base = (kt & 1) * 32 + k4;
      float4 lo = valid ? *(const float4*)(src + base) : make_float4(0, 0, 0, 0);
      float4 hi = valid ? *(const float4*)(src + base + 16) : make_float4(0, 0, 0, 0);
      bf16x8 a;
      a[0] = f2bf(lo.x); a[1] = f2bf(lo.y); a[2] = f2bf(lo.z); a[3] = f2bf(lo.w);
      a[4] = f2bf(hi.x); a[5] = f2bf(hi.y); a[6] = f2bf(hi.z); a[7] = f2bf(hi.w);
      afrag[kt] = a;
    }
#pragma unroll 1
    for (int w = 0; w < 4; ++w) {
      const uint4* wfp = (const uint4*)na.wf + (size_t)w * 2048;
      const float* bp = na.bias[w];
      void* op = na.outp[w];
#pragma unroll
      for (int nt = 0; nt < 8; ++nt) {
        bf16x8 bfrag[4];
#pragma unroll
        for (int kt = 0; kt < 4; ++kt)
          *(uint4*)&bfrag[kt] = wfp[(nt * 4 + kt) * 64 + lane];
        f32x4 acc = {0.f, 0.f, 0.f, 0.f};
#pragma unroll
        for (int kt = 0; kt < 4; ++kt)
          acc = __builtin_amdgcn_mfma_f32_16x16x32_bf16(afrag[kt], bfrag[kt], acc, 0, 0, 0);
        int col = nt * 16 + (lane & 15);
        float bias = bp[col];
#pragma unroll
        for (int reg = 0; reg < 4; ++reg) {
          int orow = tile * 16 + (lane >> 4) * 4 + reg;
          if (orow < N) {
            float vv = acc[reg] + bias;
            if (w < 3) ((short*)op)[(size_t)orow * 128 + col] = f2bf(vv);
            else       ((float*)op)[(size_t)orow * 128 + col] = vv;
          }
        }
      }
    }
  }
}

// ---- edge GEMM over dst-sorted edges: e_s[pos] = edge_attr @ We -----------
__global__ __launch_bounds__(256, 1) void k_egemm(
    const float* __restrict__ lu, const float* __restrict__ t,
    const float* __restrict__ msg, const float* __restrict__ tw,
    const float* __restrict__ tb, const short* __restrict__ wf,
    const int* __restrict__ sorted, const int* __restrict__ src_s,
    short* __restrict__ e_s, int E) {
  const int lane = threadIdx.x & 63;
  const int wv = threadIdx.x >> 6;

  bf16x8 bfrag[8][4];
  const uint4* wfp = (const uint4*)wf + (size_t)4 * 2048;   // mat 4 = We
#pragma unroll
  for (int nt = 0; nt < 8; ++nt)
#pragma unroll
    for (int kt = 0; kt < 4; ++kt)
      *(uint4*)&bfrag[nt][kt] = wfp[(nt * 4 + kt) * 64 + lane];

  const int k4 = (lane >> 4) * 4;
  float twv[16], tbv[16];
#pragma unroll
  for (int kt = 0; kt < 2; ++kt) {
    int base = kt * 32 + k4;
    *(float4*)&twv[kt * 8]     = *(const float4*)(tw + base);
    *(float4*)&twv[kt * 8 + 4] = *(const float4*)(tw + base + 16);
    *(float4*)&tbv[kt * 8]     = *(const float4*)(tb + base);
    *(float4*)&tbv[kt * 8 + 4] = *(const float4*)(tb + base + 16);
  }

  const int ntiles = (E + 15) / 16;
  const int nwaves = gridDim.x * 4;
  for (int tile = blockIdx.x * 4 + wv; tile < ntiles; tile += nwaves) {
    const int e0 = tile * 16;
    int eidv = 0, srcv = 0;
    float relt = 0.f;
    if (lane < 16 && e0 + lane < E) {
      eidv = sorted[e0 + lane];
      srcv = src_s[e0 + lane];
      relt = lu[srcv] - t[eidv];
    }
    const int r = lane & 15;
    float my_relt = __shfl(relt, r);
    int eid_r = __shfl(eidv, r);
    bool rvalid = (e0 + r) < E;

    bf16x8 afrag[4];
#pragma unroll
    for (int kt = 0; kt < 2; ++kt) {
      bf16x8 a;
#pragma unroll
      for (int j = 0; j < 8; ++j)
        a[j] = f2bf(__cosf(my_relt * twv[kt * 8 + j] + tbv[kt * 8 + j]));
      afrag[kt] = a;
    }
    const float* mr = msg + (size_t)eid_r * 64;
#pragma unroll
    for (int kt = 2; kt < 4; ++kt) {
      int base = (kt - 2) * 32 + k4;
      float4 lo = rvalid ? *(const float4*)(mr + base) : make_float4(0, 0, 0, 0);
      float4 hi = rvalid ? *(const float4*)(mr + base + 16) : make_float4(0, 0, 0, 0);
      bf16x8 a;
      a[0] = f2bf(lo.x); a[1] = f2bf(lo.y); a[2] = f2bf(lo.z); a[3] = f2bf(lo.w);
      a[4] = f2bf(hi.x); a[5] = f2bf(hi.y); a[6] = f2bf(hi.z); a[7] = f2bf(hi.w);
      afrag[kt] = a;
    }

#pragma unroll
    for (int nt = 0; nt < 8; ++nt) {
      f32x4 acc = {0.f, 0.f, 0.f, 0.f};
#pragma unroll
      for (int kt = 0; kt < 4; ++kt)
        acc = __builtin_amdgcn_mfma_f32_16x16x32_bf16(afrag[nt == 0 ? kt : kt], bfrag[nt][kt], acc, 0, 0, 0);
      int col = nt * 16 + (lane & 15);
#pragma unroll
      for (int reg = 0; reg < 4; ++reg) {
        int er = e0 + (lane >> 4) * 4 + reg;
        if (er < E) e_s[(size_t)er * 128 + col] = f2bf(acc[reg]);
      }
    }
  }
}

// ---- per-dst fused online-softmax aggregation -----------------------------
// wave per node; lane owns channel pair c2=2*lane -> head h = lane>>3.
// per edge: coalesced k/v/e row loads, 8-lane shfl dot, online rescale.
__global__ __launch_bounds__(256) void k_agg(
    const int* __restrict__ offs, const int* __restrict__ src_s,
    const short* __restrict__ e_s, const short* __restrict__ qb,
    const short* __restrict__ kb, const short* __restrict__ vb,
    float* __restrict__ out, int N) {
  __shared__ int lds_vo[4][64];
  const int wave = threadIdx.x >> 6;
  const int lane = threadIdx.x & 63;
  const int n = blockIdx.x * 4 + wave;
  if (n >= N) return;
  const int off = offs[n], end = offs[n + 1];
  if (end == off) return;                 // out keeps skip value
  const int c2 = lane * 2;

  unsigned qv = *(const unsigned*)(qb + (size_t)n * 128 + c2);
  const float q0 = bf2f((short)(qv & 0xffff));
  const float q1 = bf2f((short)(qv >> 16));

  float m = -1e30f, s = 0.f, acc0 = 0.f, acc1 = 0.f;

  for (int c0 = off; c0 < end; c0 += 64) {
    const int cnt = min(64, end - c0);
    if (lane < cnt) lds_vo[wave][lane] = src_s[c0 + lane] * 128;
    for (int j = 0; j < cnt; ++j) {
      const int vo = lds_vo[wave][j];
      unsigned ev = *(const unsigned*)(e_s + (size_t)(c0 + j) * 128 + c2);
      unsigned kv = *(const unsigned*)(kb + vo + c2);
      unsigned vv = *(const unsigned*)(vb + vo + c2);
      float e0f = bf2f((short)(ev & 0xffff)), e1f = bf2f((short)(ev >> 16));
      float k0f = bf2f((short)(kv & 0xffff)), k1f = bf2f((short)(kv >> 16));
      float v0f = bf2f((short)(vv & 0xffff)), v1f = bf2f((short)(vv >> 16));
      float part = q0 * (k0f + e0f) + q1 * (k1f + e1f);
      part += __shfl_xor(part, 1);
      part += __shfl_xor(part, 2);
      part += __shfl_xor(part, 4);        // sum over the 8-lane head group
      float l = part * 0.25f;             // / sqrt(HEAD_DIM=16)
      float mn = fmaxf(m, l);
      float sc = __expf(m - mn);
      float p  = __expf(l - mn);
      s = s * sc + p;
      m = mn;
      acc0 = acc0 * sc + p * (v0f + e0f);
      acc1 = acc1 * sc + p * (v1f + e1f);
    }
  }
  float r = 1.f / (s + 1e-16f);
  float2 o = *(float2*)(out + (size_t)n * 128 + c2);
  o.x += acc0 * r;
  o.y += acc1 * r;
  *(float2*)(out + (size_t)n * 128 + c2) = o;
}

extern "C" void kernel_launch(void* const* d_in, const int* in_sizes, int n_in,
                              void* d_out, int out_size, void* d_ws, size_t ws_size,
                              hipStream_t stream) {
  const float* feats = (const float*)d_in[0];
  const float* x     = (const float*)d_in[1];
  const float* lu    = (const float*)d_in[2];
  const int*   ei    = (const int*)d_in[3];
  const float* t     = (const float*)d_in[4];
  const float* msg   = (const float*)d_in[5];
  const float* tw    = (const float*)d_in[6];
  const float* tb    = (const float*)d_in[7];
  const float* Wq    = (const float*)d_in[8];
  const float* bq    = (const float*)d_in[9];
  const float* Wk    = (const float*)d_in[10];
  const float* bk    = (const float*)d_in[11];
  const float* Wv    = (const float*)d_in[12];
  const float* bv    = (const float*)d_in[13];
  const float* We    = (const float*)d_in[14];
  const float* Wskip = (const float*)d_in[15];
  const float* bskip = (const float*)d_in[16];
  float* out = (float*)d_out;
  const int N = in_sizes[2];
  const int E = in_sizes[4];

  char* ws = (char*)d_ws;
  short* wfrag = (short*)ws; ws += 5 * 2048 * 16;            // 160 KB
  short* qb    = (short*)ws; ws += (size_t)N * 128 * 2;
  short* kbuf  = (short*)ws; ws += (size_t)N * 128 * 2;
  short* vbuf  = (short*)ws; ws += (size_t)N * 128 * 2;
  short* e_s   = (short*)ws; ws += (size_t)E * 128 * 2;
  int* counts  = (int*)ws;   ws += (size_t)(N + 1) * 4;
  int* offs    = (int*)ws;   ws += (size_t)(N + 1) * 4;
  int* cursor  = (int*)ws;   ws += (size_t)N * 4;
  int* sorted  = (int*)ws;   ws += (size_t)E * 4;
  int* src_s   = (int*)ws;   ws += (size_t)E * 4;
  int* bsum    = (int*)ws;   ws += 128 * 4;
  int* bpre    = (int*)ws;   ws += 128 * 4;

  const int nb = (N + 1023) / 1024;

  hipMemsetAsync(counts, 0, (size_t)(N + 1) * 4, stream);
  k_hist<<<(E + 255) / 256, 256, 0, stream>>>(ei, counts, E);
  k_bsum<<<nb, 1024, 0, stream>>>(counts, bsum, N);
  k_bscan<<<1, 128, 0, stream>>>(bsum, bpre, nb);
  k_scan2<<<nb, 1024, 0, stream>>>(counts, bpre, offs, cursor, N);
  k_scatter<<<(E + 255) / 256, 256, 0, stream>>>(ei, cursor, sorted, src_s, E);

  PrepArgs pa;
  pa.W[0] = Wq; pa.W[1] = Wk; pa.W[2] = Wv; pa.W[3] = Wskip; pa.W[4] = We;
  k_prep<<<40, 256, 0, stream>>>(pa, wfrag);

  NodeArgs na;
  na.wf = wfrag;
  na.bias[0] = bq; na.bias[1] = bk; na.bias[2] = bv; na.bias[3] = bskip;
  na.outp[0] = qb; na.outp[1] = kbuf; na.outp[2] = vbuf; na.outp[3] = out;
  k_node<<<512, 256, 0, stream>>>(x, feats, na, N);

  k_egemm<<<1024, 256, 0, stream>>>(lu, t, msg, tw, tb, wfrag,
                                    sorted, src_s, e_s, E);
  k_agg<<<(N + 3) / 4, 256, 0, stream>>>(offs, src_s, e_s, qb, kbuf, vbuf,
                                         out, N);
}

// Round 5
// 335.556 us; speedup vs baseline: 4.2707x; 1.0589x over previous
//
#include <hip/hip_runtime.h>
#include <math.h>

// ---------------------------------------------------------------------------
// TGN GraphAttentionEmbedding, MFMA bf16, dst-sorted dataflow:
//   sort edges by dst (hist/scan/scatter) -> sorted[], src_s[]
//   k_node : h=[x,feats]; q/k/v (bf16) + skip (f32->out), 4 GEMMs fused,
//            coalesced stores via per-wave LDS transpose
//   k_egemm: e_s[pos] = [cos((lu[src]-t)tw+tb), msg] @ We  (same store path)
//   k_agg  : per dst node, fused online-softmax attention aggregate
// ---------------------------------------------------------------------------

typedef __attribute__((ext_vector_type(8))) short bf16x8;
typedef __attribute__((ext_vector_type(4))) float f32x4;

__device__ inline short f2bf(float f) {
  unsigned u = __float_as_uint(f);
  u += 0x7fff + ((u >> 16) & 1);     // round-to-nearest-even
  return (short)(u >> 16);
}
__device__ inline float bf2f(short s) {
  return __uint_as_float(((unsigned)(unsigned short)s) << 16);
}

// ---- sort edges by dst ----------------------------------------------------
__global__ void k_hist(const int* __restrict__ ei, int* __restrict__ counts, int E) {
  int i = blockIdx.x * 256 + threadIdx.x;
  if (i < E) atomicAdd(&counts[ei[E + i]], 1);
}

__global__ __launch_bounds__(1024) void k_bsum(const int* __restrict__ counts,
                                               int* __restrict__ bsum, int N) {
  int i = blockIdx.x * 1024 + threadIdx.x;
  int v = (i < N) ? counts[i] : 0;
  for (int d = 32; d; d >>= 1) v += __shfl_down(v, d);
  __shared__ int ws_[16];
  int lane = threadIdx.x & 63, wv = threadIdx.x >> 6;
  if (lane == 0) ws_[wv] = v;
  __syncthreads();
  if (threadIdx.x == 0) {
    int s = 0;
    for (int j = 0; j < 16; ++j) s += ws_[j];
    bsum[blockIdx.x] = s;
  }
}

__global__ __launch_bounds__(128) void k_bscan(const int* __restrict__ bsum,
                                               int* __restrict__ bpre, int nb) {
  __shared__ int sh[128];
  int t = threadIdx.x;
  sh[t] = (t < nb) ? bsum[t] : 0;
  __syncthreads();
  for (int d = 1; d < 128; d <<= 1) {
    int v = (t >= d) ? sh[t - d] : 0;
    __syncthreads();
    sh[t] += v;
    __syncthreads();
  }
  if (t < nb) bpre[t] = (t == 0) ? 0 : sh[t - 1];
}

__global__ __launch_bounds__(1024) void k_scan2(const int* __restrict__ counts,
                                                const int* __restrict__ bpre,
                                                int* __restrict__ offs,
                                                int* __restrict__ cursor, int N) {
  __shared__ int sh[1024];
  int t = threadIdx.x;
  int i = blockIdx.x * 1024 + t;
  int v = (i < N) ? counts[i] : 0;
  sh[t] = v;
  __syncthreads();
  for (int d = 1; d < 1024; d <<= 1) {
    int u = (t >= d) ? sh[t - d] : 0;
    __syncthreads();
    sh[t] += u;
    __syncthreads();
  }
  if (i < N) {
    int excl = bpre[blockIdx.x] + sh[t] - v;
    offs[i] = excl;
    cursor[i] = excl;
    if (i == N - 1) offs[N] = excl + v;
  }
}

__global__ void k_scatter(const int* __restrict__ ei, int* __restrict__ cursor,
                          int* __restrict__ sorted, int* __restrict__ src_s, int E) {
  int i = blockIdx.x * 256 + threadIdx.x;
  if (i < E) {
    int pos = atomicAdd(&cursor[ei[E + i]], 1);
    sorted[pos] = i;
    src_s[pos] = ei[i];
  }
}

// ---- prep: shuffle W (f32, [K=128][N=128]) into bf16 MFMA B-frag layout ---
struct PrepArgs { const float* W[5]; };
__global__ void k_prep(PrepArgs pa, short* __restrict__ wf) {
  int tid = blockIdx.x * 256 + threadIdx.x;
  if (tid >= 5 * 8 * 4 * 64) return;
  int lane = tid & 63;
  int kt = (tid >> 6) & 3;
  int nt = (tid >> 8) & 7;
  int mat = tid >> 11;
  const float* W = pa.W[mat];
  int n = nt * 16 + (lane & 15);
  short v[8];
#pragma unroll
  for (int j = 0; j < 8; ++j) {
    int k = kt * 32 + ((j >> 2) * 16) + ((lane >> 4) * 4) + (j & 3);
    v[j] = f2bf(W[k * 128 + n]);
  }
  ((uint4*)wf)[tid] = *(uint4*)v;
}

// ---- node GEMMs, all 4 mats fused; LDS-transposed coalesced stores --------
struct NodeArgs {
  const short* wf;
  const float* bias[4];
  void* outp[4];
};

__global__ __launch_bounds__(256, 2) void k_node(
    const float* __restrict__ x, const float* __restrict__ feats,
    NodeArgs na, int N) {
  __shared__ char lds[4][8192];           // per-wave slice, no barriers needed
  const int lane = threadIdx.x & 63;
  const int wv = threadIdx.x >> 6;
  const int tile = blockIdx.x * 4 + wv;
  const int ntiles = (N + 15) / 16;
  if (tile >= ntiles) return;
  char* myl = lds[wv];

  const int arow = lane & 15;
  const int k4 = (lane >> 4) * 4;
  int row = tile * 16 + arow;
  bool valid = row < N;
  const float* xr = x + (size_t)row * 64;
  const float* fr = feats + (size_t)row * 64;
  bf16x8 afrag[4];
#pragma unroll
  for (int kt = 0; kt < 4; ++kt) {
    const float* src = (kt < 2) ? xr : fr;
    int base = (kt & 1) * 32 + k4;
    float4 lo = valid ? *(const float4*)(src + base) : make_float4(0, 0, 0, 0);
    float4 hi = valid ? *(const float4*)(src + base + 16) : make_float4(0, 0, 0, 0);
    bf16x8 a;
    a[0] = f2bf(lo.x); a[1] = f2bf(lo.y); a[2] = f2bf(lo.z); a[3] = f2bf(lo.w);
    a[4] = f2bf(hi.x); a[5] = f2bf(hi.y); a[6] = f2bf(hi.z); a[7] = f2bf(hi.w);
    afrag[kt] = a;
  }

#pragma unroll 1
  for (int w = 0; w < 4; ++w) {
    const uint4* wfp = (const uint4*)na.wf + (size_t)w * 2048;
    const float* bp = na.bias[w];
#pragma unroll
    for (int nt = 0; nt < 8; ++nt) {
      bf16x8 bfrag[4];
#pragma unroll
      for (int kt = 0; kt < 4; ++kt)
        *(uint4*)&bfrag[kt] = wfp[(nt * 4 + kt) * 64 + lane];
      f32x4 acc = {0.f, 0.f, 0.f, 0.f};
#pragma unroll
      for (int kt = 0; kt < 4; ++kt)
        acc = __builtin_amdgcn_mfma_f32_16x16x32_bf16(afrag[kt], bfrag[kt], acc, 0, 0, 0);
      int col = nt * 16 + (lane & 15);
      float bias = bp[col];
#pragma unroll
      for (int reg = 0; reg < 4; ++reg) {
        int r = (lane >> 4) * 4 + reg;
        float vv = acc[reg] + bias;
        if (w < 3) ((short*)myl)[r * 128 + col] = f2bf(vv);
        else       ((float*)myl)[r * 128 + col] = vv;
      }
    }
    // drain LDS -> global, coalesced
    if (w < 3) {
      short* op = (short*)na.outp[w];
#pragma unroll
      for (int i = 0; i < 8; ++i) {
        int r = i * 2 + (lane >> 5);
        int orow = tile * 16 + r;
        uint2 val = ((const uint2*)myl)[i * 64 + lane];
        if (orow < N)
          *(uint2*)(op + (size_t)orow * 128 + (lane & 31) * 4) = val;
      }
    } else {
      float* op = (float*)na.outp[3];
#pragma unroll
      for (int i = 0; i < 8; ++i) {
        int r = i * 2 + (lane >> 5);
        int orow = tile * 16 + r;
        uint4 val = ((const uint4*)myl)[i * 64 + lane];
        if (orow < N)
          *(uint4*)(op + (size_t)orow * 128 + (lane & 31) * 4) = val;
      }
    }
  }
}

// ---- edge GEMM over dst-sorted edges: e_s[pos] = edge_attr @ We -----------
__global__ __launch_bounds__(256, 2) void k_egemm(
    const float* __restrict__ lu, const float* __restrict__ t,
    const float* __restrict__ msg, const float* __restrict__ tw,
    const float* __restrict__ tb, const short* __restrict__ wf,
    const int* __restrict__ sorted, const int* __restrict__ src_s,
    short* __restrict__ e_s, int E) {
  __shared__ char lds[4][4096];           // per-wave 16x128 bf16
  const int lane = threadIdx.x & 63;
  const int wv = threadIdx.x >> 6;
  const int tile = blockIdx.x * 4 + wv;
  const int ntiles = (E + 15) / 16;
  if (tile >= ntiles) return;
  char* myl = lds[wv];
  const uint4* wfp = (const uint4*)wf + (size_t)4 * 2048;   // mat 4 = We

  const int k4 = (lane >> 4) * 4;
  float twv[16], tbv[16];
#pragma unroll
  for (int kt = 0; kt < 2; ++kt) {
    int base = kt * 32 + k4;
    *(float4*)&twv[kt * 8]     = *(const float4*)(tw + base);
    *(float4*)&twv[kt * 8 + 4] = *(const float4*)(tw + base + 16);
    *(float4*)&tbv[kt * 8]     = *(const float4*)(tb + base);
    *(float4*)&tbv[kt * 8 + 4] = *(const float4*)(tb + base + 16);
  }

  const int e0 = tile * 16;
  int eidv = 0, srcv = 0;
  float relt = 0.f;
  if (lane < 16 && e0 + lane < E) {
    eidv = sorted[e0 + lane];
    srcv = src_s[e0 + lane];
    relt = lu[srcv] - t[eidv];
  }
  const int r = lane & 15;
  float my_relt = __shfl(relt, r);
  int eid_r = __shfl(eidv, r);
  bool rvalid = (e0 + r) < E;

  bf16x8 afrag[4];
#pragma unroll
  for (int kt = 0; kt < 2; ++kt) {
    bf16x8 a;
#pragma unroll
    for (int j = 0; j < 8; ++j)
      a[j] = f2bf(__cosf(my_relt * twv[kt * 8 + j] + tbv[kt * 8 + j]));
    afrag[kt] = a;
  }
  const float* mr = msg + (size_t)eid_r * 64;
#pragma unroll
  for (int kt = 2; kt < 4; ++kt) {
    int base = (kt - 2) * 32 + k4;
    float4 lo = rvalid ? *(const float4*)(mr + base) : make_float4(0, 0, 0, 0);
    float4 hi = rvalid ? *(const float4*)(mr + base + 16) : make_float4(0, 0, 0, 0);
    bf16x8 a;
    a[0] = f2bf(lo.x); a[1] = f2bf(lo.y); a[2] = f2bf(lo.z); a[3] = f2bf(lo.w);
    a[4] = f2bf(hi.x); a[5] = f2bf(hi.y); a[6] = f2bf(hi.z); a[7] = f2bf(hi.w);
    afrag[kt] = a;
  }

#pragma unroll
  for (int nt = 0; nt < 8; ++nt) {
    bf16x8 bfrag[4];
#pragma unroll
    for (int kt = 0; kt < 4; ++kt)
      *(uint4*)&bfrag[kt] = wfp[(nt * 4 + kt) * 64 + lane];
    f32x4 acc = {0.f, 0.f, 0.f, 0.f};
#pragma unroll
    for (int kt = 0; kt < 4; ++kt)
      acc = __builtin_amdgcn_mfma_f32_16x16x32_bf16(afrag[kt], bfrag[kt], acc, 0, 0, 0);
    int col = nt * 16 + (lane & 15);
#pragma unroll
    for (int reg = 0; reg < 4; ++reg) {
      int rr = (lane >> 4) * 4 + reg;
      ((short*)myl)[rr * 128 + col] = f2bf(acc[reg]);
    }
  }
#pragma unroll
  for (int i = 0; i < 8; ++i) {
    int rr = i * 2 + (lane >> 5);
    int er = e0 + rr;
    uint2 val = ((const uint2*)myl)[i * 64 + lane];
    if (er < E)
      *(uint2*)(e_s + (size_t)er * 128 + (lane & 31) * 4) = val;
  }
}

// ---- per-dst fused online-softmax aggregation -----------------------------
__global__ __launch_bounds__(256) void k_agg(
    const int* __restrict__ offs, const int* __restrict__ src_s,
    const short* __restrict__ e_s, const short* __restrict__ qb,
    const short* __restrict__ kb, const short* __restrict__ vb,
    float* __restrict__ out, int N) {
  __shared__ int lds_vo[4][64];
  const int wave = threadIdx.x >> 6;
  const int lane = threadIdx.x & 63;
  const int n = blockIdx.x * 4 + wave;
  if (n >= N) return;
  const int off = offs[n], end = offs[n + 1];
  if (end == off) return;                 // out keeps skip value
  const int c2 = lane * 2;

  unsigned qv = *(const unsigned*)(qb + (size_t)n * 128 + c2);
  const float q0 = bf2f((short)(qv & 0xffff));
  const float q1 = bf2f((short)(qv >> 16));

  float m = -1e30f, s = 0.f, acc0 = 0.f, acc1 = 0.f;

  for (int c0 = off; c0 < end; c0 += 64) {
    const int cnt = min(64, end - c0);
    if (lane < cnt) lds_vo[wave][lane] = src_s[c0 + lane] * 128;
    for (int j = 0; j < cnt; ++j) {
      const int vo = lds_vo[wave][j];
      unsigned ev = *(const unsigned*)(e_s + (size_t)(c0 + j) * 128 + c2);
      unsigned kv = *(const unsigned*)(kb + vo + c2);
      unsigned vv = *(const unsigned*)(vb + vo + c2);
      float e0f = bf2f((short)(ev & 0xffff)), e1f = bf2f((short)(ev >> 16));
      float k0f = bf2f((short)(kv & 0xffff)), k1f = bf2f((short)(kv >> 16));
      float v0f = bf2f((short)(vv & 0xffff)), v1f = bf2f((short)(vv >> 16));
      float part = q0 * (k0f + e0f) + q1 * (k1f + e1f);
      part += __shfl_xor(part, 1);
      part += __shfl_xor(part, 2);
      part += __shfl_xor(part, 4);        // sum over the 8-lane head group
      float l = part * 0.25f;             // / sqrt(HEAD_DIM=16)
      float mn = fmaxf(m, l);
      float sc = __expf(m - mn);
      float p  = __expf(l - mn);
      s = s * sc + p;
      m = mn;
      acc0 = acc0 * sc + p * (v0f + e0f);
      acc1 = acc1 * sc + p * (v1f + e1f);
    }
  }
  float r = 1.f / (s + 1e-16f);
  float2 o = *(float2*)(out + (size_t)n * 128 + c2);
  o.x += acc0 * r;
  o.y += acc1 * r;
  *(float2*)(out + (size_t)n * 128 + c2) = o;
}

extern "C" void kernel_launch(void* const* d_in, const int* in_sizes, int n_in,
                              void* d_out, int out_size, void* d_ws, size_t ws_size,
                              hipStream_t stream) {
  const float* feats = (const float*)d_in[0];
  const float* x     = (const float*)d_in[1];
  const float* lu    = (const float*)d_in[2];
  const int*   ei    = (const int*)d_in[3];
  const float* t     = (const float*)d_in[4];
  const float* msg   = (const float*)d_in[5];
  const float* tw    = (const float*)d_in[6];
  const float* tb    = (const float*)d_in[7];
  const float* Wq    = (const float*)d_in[8];
  const float* bq    = (const float*)d_in[9];
  const float* Wk    = (const float*)d_in[10];
  const float* bk    = (const float*)d_in[11];
  const float* Wv    = (const float*)d_in[12];
  const float* bv    = (const float*)d_in[13];
  const float* We    = (const float*)d_in[14];
  const float* Wskip = (const float*)d_in[15];
  const float* bskip = (const float*)d_in[16];
  float* out = (float*)d_out;
  const int N = in_sizes[2];
  const int E = in_sizes[4];

  char* ws = (char*)d_ws;
  short* wfrag = (short*)ws; ws += 5 * 2048 * 16;            // 160 KB
  short* qb    = (short*)ws; ws += (size_t)N * 128 * 2;
  short* kbuf  = (short*)ws; ws += (size_t)N * 128 * 2;
  short* vbuf  = (short*)ws; ws += (size_t)N * 128 * 2;
  short* e_s   = (short*)ws; ws += (size_t)E * 128 * 2;
  int* counts  = (int*)ws;   ws += (size_t)(N + 1) * 4;
  int* offs    = (int*)ws;   ws += (size_t)(N + 1) * 4;
  int* cursor  = (int*)ws;   ws += (size_t)N * 4;
  int* sorted  = (int*)ws;   ws += (size_t)E * 4;
  int* src_s   = (int*)ws;   ws += (size_t)E * 4;
  int* bsum    = (int*)ws;   ws += 128 * 4;
  int* bpre    = (int*)ws;   ws += 128 * 4;

  const int nb = (N + 1023) / 1024;

  hipMemsetAsync(counts, 0, (size_t)(N + 1) * 4, stream);
  k_hist<<<(E + 255) / 256, 256, 0, stream>>>(ei, counts, E);
  k_bsum<<<nb, 1024, 0, stream>>>(counts, bsum, N);
  k_bscan<<<1, 128, 0, stream>>>(bsum, bpre, nb);
  k_scan2<<<nb, 1024, 0, stream>>>(counts, bpre, offs, cursor, N);
  k_scatter<<<(E + 255) / 256, 256, 0, stream>>>(ei, cursor, sorted, src_s, E);

  PrepArgs pa;
  pa.W[0] = Wq; pa.W[1] = Wk; pa.W[2] = Wv; pa.W[3] = Wskip; pa.W[4] = We;
  k_prep<<<40, 256, 0, stream>>>(pa, wfrag);

  NodeArgs na;
  na.wf = wfrag;
  na.bias[0] = bq; na.bias[1] = bk; na.bias[2] = bv; na.bias[3] = bskip;
  na.outp[0] = qb; na.outp[1] = kbuf; na.outp[2] = vbuf; na.outp[3] = out;
  const int node_tiles = (N + 15) / 16;
  k_node<<<(node_tiles + 3) / 4, 256, 0, stream>>>(x, feats, na, N);

  const int edge_tiles = (E + 15) / 16;
  k_egemm<<<(edge_tiles + 3) / 4, 256, 0, stream>>>(lu, t, msg, tw, tb, wfrag,
                                                    sorted, src_s, e_s, E);
  k_agg<<<(N + 3) / 4, 256, 0, stream>>>(offs, src_s, e_s, qb, kbuf, vbuf,
                                         out, N);
}

// Round 6
// 325.672 us; speedup vs baseline: 4.4004x; 1.0303x over previous
//
#include <hip/hip_runtime.h>
#include <math.h>

// ---------------------------------------------------------------------------
// TGN GraphAttentionEmbedding, MFMA bf16, dst-sorted dataflow:
//   sort edges by dst (hist/scan/scatter) -> rank[] (orig->sorted), src_s[]
//   k_node : h=[x,feats]; q/k/v (bf16) + skip (f32->out), 4 GEMMs fused,
//            coalesced stores via per-wave LDS transpose
//   k_egemm: original-order streaming GEMM, rows scattered to e_s[rank[i]]
//   k_agg  : per dst node, fused online-softmax attention aggregate
// ---------------------------------------------------------------------------

typedef __attribute__((ext_vector_type(8))) short bf16x8;
typedef __attribute__((ext_vector_type(4))) float f32x4;

__device__ inline short f2bf(float f) {
  unsigned u = __float_as_uint(f);
  u += 0x7fff + ((u >> 16) & 1);     // round-to-nearest-even
  return (short)(u >> 16);
}
__device__ inline float bf2f(short s) {
  return __uint_as_float(((unsigned)(unsigned short)s) << 16);
}

// ---- sort edges by dst ----------------------------------------------------
__global__ void k_hist(const int* __restrict__ ei, int* __restrict__ counts, int E) {
  int i = blockIdx.x * 256 + threadIdx.x;
  if (i < E) atomicAdd(&counts[ei[E + i]], 1);
}

__global__ __launch_bounds__(1024) void k_bsum(const int* __restrict__ counts,
                                               int* __restrict__ bsum, int N) {
  int i = blockIdx.x * 1024 + threadIdx.x;
  int v = (i < N) ? counts[i] : 0;
  for (int d = 32; d; d >>= 1) v += __shfl_down(v, d);
  __shared__ int ws_[16];
  int lane = threadIdx.x & 63, wv = threadIdx.x >> 6;
  if (lane == 0) ws_[wv] = v;
  __syncthreads();
  if (threadIdx.x == 0) {
    int s = 0;
    for (int j = 0; j < 16; ++j) s += ws_[j];
    bsum[blockIdx.x] = s;
  }
}

__global__ __launch_bounds__(128) void k_bscan(const int* __restrict__ bsum,
                                               int* __restrict__ bpre, int nb) {
  __shared__ int sh[128];
  int t = threadIdx.x;
  sh[t] = (t < nb) ? bsum[t] : 0;
  __syncthreads();
  for (int d = 1; d < 128; d <<= 1) {
    int v = (t >= d) ? sh[t - d] : 0;
    __syncthreads();
    sh[t] += v;
    __syncthreads();
  }
  if (t < nb) bpre[t] = (t == 0) ? 0 : sh[t - 1];
}

__global__ __launch_bounds__(1024) void k_scan2(const int* __restrict__ counts,
                                                const int* __restrict__ bpre,
                                                int* __restrict__ offs,
                                                int* __restrict__ cursor, int N) {
  __shared__ int sh[1024];
  int t = threadIdx.x;
  int i = blockIdx.x * 1024 + t;
  int v = (i < N) ? counts[i] : 0;
  sh[t] = v;
  __syncthreads();
  for (int d = 1; d < 1024; d <<= 1) {
    int u = (t >= d) ? sh[t - d] : 0;
    __syncthreads();
    sh[t] += u;
    __syncthreads();
  }
  if (i < N) {
    int excl = bpre[blockIdx.x] + sh[t] - v;
    offs[i] = excl;
    cursor[i] = excl;
    if (i == N - 1) offs[N] = excl + v;
  }
}

// rank[i]: sorted position of original edge i; src_s[pos]: src of that edge
__global__ void k_scatter(const int* __restrict__ ei, int* __restrict__ cursor,
                          int* __restrict__ rank, int* __restrict__ src_s, int E) {
  int i = blockIdx.x * 256 + threadIdx.x;
  if (i < E) {
    int pos = atomicAdd(&cursor[ei[E + i]], 1);
    rank[i] = pos;
    src_s[pos] = ei[i];
  }
}

// ---- prep: shuffle W (f32, [K=128][N=128]) into bf16 MFMA B-frag layout ---
struct PrepArgs { const float* W[5]; };
__global__ void k_prep(PrepArgs pa, short* __restrict__ wf) {
  int tid = blockIdx.x * 256 + threadIdx.x;
  if (tid >= 5 * 8 * 4 * 64) return;
  int lane = tid & 63;
  int kt = (tid >> 6) & 3;
  int nt = (tid >> 8) & 7;
  int mat = tid >> 11;
  const float* W = pa.W[mat];
  int n = nt * 16 + (lane & 15);
  short v[8];
#pragma unroll
  for (int j = 0; j < 8; ++j) {
    int k = kt * 32 + ((j >> 2) * 16) + ((lane >> 4) * 4) + (j & 3);
    v[j] = f2bf(W[k * 128 + n]);
  }
  ((uint4*)wf)[tid] = *(uint4*)v;
}

// ---- node GEMMs, all 4 mats fused; LDS-transposed coalesced stores --------
struct NodeArgs {
  const short* wf;
  const float* bias[4];
  void* outp[4];
};

__global__ __launch_bounds__(256, 2) void k_node(
    const float* __restrict__ x, const float* __restrict__ feats,
    NodeArgs na, int N) {
  __shared__ char lds[4][8192];           // per-wave slice, no barriers needed
  const int lane = threadIdx.x & 63;
  const int wv = threadIdx.x >> 6;
  const int tile = blockIdx.x * 4 + wv;
  const int ntiles = (N + 15) / 16;
  if (tile >= ntiles) return;
  char* myl = lds[wv];

  const int arow = lane & 15;
  const int k4 = (lane >> 4) * 4;
  int row = tile * 16 + arow;
  bool valid = row < N;
  const float* xr = x + (size_t)row * 64;
  const float* fr = feats + (size_t)row * 64;
  bf16x8 afrag[4];
#pragma unroll
  for (int kt = 0; kt < 4; ++kt) {
    const float* src = (kt < 2) ? xr : fr;
    int base = (kt & 1) * 32 + k4;
    float4 lo = valid ? *(const float4*)(src + base) : make_float4(0, 0, 0, 0);
    float4 hi = valid ? *(const float4*)(src + base + 16) : make_float4(0, 0, 0, 0);
    bf16x8 a;
    a[0] = f2bf(lo.x); a[1] = f2bf(lo.y); a[2] = f2bf(lo.z); a[3] = f2bf(lo.w);
    a[4] = f2bf(hi.x); a[5] = f2bf(hi.y); a[6] = f2bf(hi.z); a[7] = f2bf(hi.w);
    afrag[kt] = a;
  }

#pragma unroll 1
  for (int w = 0; w < 4; ++w) {
    const uint4* wfp = (const uint4*)na.wf + (size_t)w * 2048;
    const float* bp = na.bias[w];
#pragma unroll
    for (int nt = 0; nt < 8; ++nt) {
      bf16x8 bfrag[4];
#pragma unroll
      for (int kt = 0; kt < 4; ++kt)
        *(uint4*)&bfrag[kt] = wfp[(nt * 4 + kt) * 64 + lane];
      f32x4 acc = {0.f, 0.f, 0.f, 0.f};
#pragma unroll
      for (int kt = 0; kt < 4; ++kt)
        acc = __builtin_amdgcn_mfma_f32_16x16x32_bf16(afrag[kt], bfrag[kt], acc, 0, 0, 0);
      int col = nt * 16 + (lane & 15);
      float bias = bp[col];
#pragma unroll
      for (int reg = 0; reg < 4; ++reg) {
        int r = (lane >> 4) * 4 + reg;
        float vv = acc[reg] + bias;
        if (w < 3) ((short*)myl)[r * 128 + col] = f2bf(vv);
        else       ((float*)myl)[r * 128 + col] = vv;
      }
    }
    // drain LDS -> global, coalesced
    if (w < 3) {
      short* op = (short*)na.outp[w];
#pragma unroll
      for (int i = 0; i < 8; ++i) {
        int r = i * 2 + (lane >> 5);
        int orow = tile * 16 + r;
        uint2 val = ((const uint2*)myl)[i * 64 + lane];
        if (orow < N)
          *(uint2*)(op + (size_t)orow * 128 + (lane & 31) * 4) = val;
      }
    } else {
      float* op = (float*)na.outp[3];
#pragma unroll
      for (int i = 0; i < 8; ++i) {
        int r = i * 2 + (lane >> 5);
        int orow = tile * 16 + r;
        uint4 val = ((const uint4*)myl)[i * 64 + lane];
        if (orow < N)
          *(uint4*)(op + (size_t)orow * 128 + (lane & 31) * 4) = val;
      }
    }
  }
}

// ---- edge GEMM in ORIGINAL edge order; rows scattered to e_s[rank[i]] ----
__global__ __launch_bounds__(256, 2) void k_egemm(
    const float* __restrict__ lu, const int* __restrict__ ei,
    const float* __restrict__ t, const float* __restrict__ msg,
    const float* __restrict__ tw, const float* __restrict__ tb,
    const short* __restrict__ wf, const int* __restrict__ rank,
    short* __restrict__ e_s, int E) {
  __shared__ char lds[4][4096];           // per-wave 16x128 bf16
  const int lane = threadIdx.x & 63;
  const int wv = threadIdx.x >> 6;
  const int tile = blockIdx.x * 4 + wv;
  const int ntiles = (E + 15) / 16;
  if (tile >= ntiles) return;
  char* myl = lds[wv];
  const uint4* wfp = (const uint4*)wf + (size_t)4 * 2048;   // mat 4 = We

  const int k4 = (lane >> 4) * 4;
  float twv[16], tbv[16];
#pragma unroll
  for (int kt = 0; kt < 2; ++kt) {
    int base = kt * 32 + k4;
    *(float4*)&twv[kt * 8]     = *(const float4*)(tw + base);
    *(float4*)&twv[kt * 8 + 4] = *(const float4*)(tw + base + 16);
    *(float4*)&tbv[kt * 8]     = *(const float4*)(tb + base);
    *(float4*)&tbv[kt * 8 + 4] = *(const float4*)(tb + base + 16);
  }

  const int e0 = tile * 16;
  int rank16 = 0;
  float relt = 0.f;
  if (lane < 16 && e0 + lane < E) {
    int src = ei[e0 + lane];                   // coalesced (orig order)
    relt = lu[src] - t[e0 + lane];             // lu: 400KB L2-resident gather
    rank16 = rank[e0 + lane];                  // coalesced
  }
  const int r = lane & 15;
  float my_relt = __shfl(relt, r);
  bool rvalid = (e0 + r) < E;

  bf16x8 afrag[4];
#pragma unroll
  for (int kt = 0; kt < 2; ++kt) {
    bf16x8 a;
#pragma unroll
    for (int j = 0; j < 8; ++j)
      a[j] = f2bf(__cosf(my_relt * twv[kt * 8 + j] + tbv[kt * 8 + j]));
    afrag[kt] = a;
  }
  const float* mr = msg + (size_t)(e0 + r) * 64;   // streaming, coalesced
#pragma unroll
  for (int kt = 2; kt < 4; ++kt) {
    int base = (kt - 2) * 32 + k4;
    float4 lo = rvalid ? *(const float4*)(mr + base) : make_float4(0, 0, 0, 0);
    float4 hi = rvalid ? *(const float4*)(mr + base + 16) : make_float4(0, 0, 0, 0);
    bf16x8 a;
    a[0] = f2bf(lo.x); a[1] = f2bf(lo.y); a[2] = f2bf(lo.z); a[3] = f2bf(lo.w);
    a[4] = f2bf(hi.x); a[5] = f2bf(hi.y); a[6] = f2bf(hi.z); a[7] = f2bf(hi.w);
    afrag[kt] = a;
  }

#pragma unroll
  for (int nt = 0; nt < 8; ++nt) {
    bf16x8 bfrag[4];
#pragma unroll
    for (int kt = 0; kt < 4; ++kt)
      *(uint4*)&bfrag[kt] = wfp[(nt * 4 + kt) * 64 + lane];
    f32x4 acc = {0.f, 0.f, 0.f, 0.f};
#pragma unroll
    for (int kt = 0; kt < 4; ++kt)
      acc = __builtin_amdgcn_mfma_f32_16x16x32_bf16(afrag[kt], bfrag[kt], acc, 0, 0, 0);
    int col = nt * 16 + (lane & 15);
#pragma unroll
    for (int reg = 0; reg < 4; ++reg) {
      int rr = (lane >> 4) * 4 + reg;
      ((short*)myl)[rr * 128 + col] = f2bf(acc[reg]);
    }
  }
#pragma unroll
  for (int i = 0; i < 8; ++i) {
    int rr = i * 2 + (lane >> 5);
    int er = e0 + rr;
    int drow = __shfl(rank16, rr);          // sorted row for this edge
    uint2 val = ((const uint2*)myl)[i * 64 + lane];
    if (er < E)
      *(uint2*)(e_s + (size_t)drow * 128 + (lane & 31) * 4) = val;
  }
}

// ---- per-dst fused online-softmax aggregation -----------------------------
__global__ __launch_bounds__(256) void k_agg(
    const int* __restrict__ offs, const int* __restrict__ src_s,
    const short* __restrict__ e_s, const short* __restrict__ qb,
    const short* __restrict__ kb, const short* __restrict__ vb,
    float* __restrict__ out, int N) {
  __shared__ int lds_vo[4][64];
  const int wave = threadIdx.x >> 6;
  const int lane = threadIdx.x & 63;
  const int n = blockIdx.x * 4 + wave;
  if (n >= N) return;
  const int off = offs[n], end = offs[n + 1];
  if (end == off) return;                 // out keeps skip value
  const int c2 = lane * 2;

  unsigned qv = *(const unsigned*)(qb + (size_t)n * 128 + c2);
  const float q0 = bf2f((short)(qv & 0xffff));
  const float q1 = bf2f((short)(qv >> 16));

  float m = -1e30f, s = 0.f, acc0 = 0.f, acc1 = 0.f;

  for (int c0 = off; c0 < end; c0 += 64) {
    const int cnt = min(64, end - c0);
    if (lane < cnt) lds_vo[wave][lane] = src_s[c0 + lane] * 128;
    for (int j = 0; j < cnt; ++j) {
      const int vo = lds_vo[wave][j];
      unsigned ev = *(const unsigned*)(e_s + (size_t)(c0 + j) * 128 + c2);
      unsigned kv = *(const unsigned*)(kb + vo + c2);
      unsigned vv = *(const unsigned*)(vb + vo + c2);
      float e0f = bf2f((short)(ev & 0xffff)), e1f = bf2f((short)(ev >> 16));
      float k0f = bf2f((short)(kv & 0xffff)), k1f = bf2f((short)(kv >> 16));
      float v0f = bf2f((short)(vv & 0xffff)), v1f = bf2f((short)(vv >> 16));
      float part = q0 * (k0f + e0f) + q1 * (k1f + e1f);
      part += __shfl_xor(part, 1);
      part += __shfl_xor(part, 2);
      part += __shfl_xor(part, 4);        // sum over the 8-lane head group
      float l = part * 0.25f;             // / sqrt(HEAD_DIM=16)
      float mn = fmaxf(m, l);
      float sc = __expf(m - mn);
      float p  = __expf(l - mn);
      s = s * sc + p;
      m = mn;
      acc0 = acc0 * sc + p * (v0f + e0f);
      acc1 = acc1 * sc + p * (v1f + e1f);
    }
  }
  float r = 1.f / (s + 1e-16f);
  float2 o = *(float2*)(out + (size_t)n * 128 + c2);
  o.x += acc0 * r;
  o.y += acc1 * r;
  *(float2*)(out + (size_t)n * 128 + c2) = o;
}

extern "C" void kernel_launch(void* const* d_in, const int* in_sizes, int n_in,
                              void* d_out, int out_size, void* d_ws, size_t ws_size,
                              hipStream_t stream) {
  const float* feats = (const float*)d_in[0];
  const float* x     = (const float*)d_in[1];
  const float* lu    = (const float*)d_in[2];
  const int*   ei    = (const int*)d_in[3];
  const float* t     = (const float*)d_in[4];
  const float* msg   = (const float*)d_in[5];
  const float* tw    = (const float*)d_in[6];
  const float* tb    = (const float*)d_in[7];
  const float* Wq    = (const float*)d_in[8];
  const float* bq    = (const float*)d_in[9];
  const float* Wk    = (const float*)d_in[10];
  const float* bk    = (const float*)d_in[11];
  const float* Wv    = (const float*)d_in[12];
  const float* bv    = (const float*)d_in[13];
  const float* We    = (const float*)d_in[14];
  const float* Wskip = (const float*)d_in[15];
  const float* bskip = (const float*)d_in[16];
  float* out = (float*)d_out;
  const int N = in_sizes[2];
  const int E = in_sizes[4];

  char* ws = (char*)d_ws;
  short* wfrag = (short*)ws; ws += 5 * 2048 * 16;            // 160 KB
  short* qb    = (short*)ws; ws += (size_t)N * 128 * 2;
  short* kbuf  = (short*)ws; ws += (size_t)N * 128 * 2;
  short* vbuf  = (short*)ws; ws += (size_t)N * 128 * 2;
  short* e_s   = (short*)ws; ws += (size_t)E * 128 * 2;
  int* counts  = (int*)ws;   ws += (size_t)(N + 1) * 4;
  int* offs    = (int*)ws;   ws += (size_t)(N + 1) * 4;
  int* cursor  = (int*)ws;   ws += (size_t)N * 4;
  int* rank    = (int*)ws;   ws += (size_t)E * 4;
  int* src_s   = (int*)ws;   ws += (size_t)E * 4;
  int* bsum    = (int*)ws;   ws += 128 * 4;
  int* bpre    = (int*)ws;   ws += 128 * 4;

  const int nb = (N + 1023) / 1024;

  hipMemsetAsync(counts, 0, (size_t)(N + 1) * 4, stream);
  k_hist<<<(E + 255) / 256, 256, 0, stream>>>(ei, counts, E);
  k_bsum<<<nb, 1024, 0, stream>>>(counts, bsum, N);
  k_bscan<<<1, 128, 0, stream>>>(bsum, bpre, nb);
  k_scan2<<<nb, 1024, 0, stream>>>(counts, bpre, offs, cursor, N);
  k_scatter<<<(E + 255) / 256, 256, 0, stream>>>(ei, cursor, rank, src_s, E);

  PrepArgs pa;
  pa.W[0] = Wq; pa.W[1] = Wk; pa.W[2] = Wv; pa.W[3] = Wskip; pa.W[4] = We;
  k_prep<<<40, 256, 0, stream>>>(pa, wfrag);

  NodeArgs na;
  na.wf = wfrag;
  na.bias[0] = bq; na.bias[1] = bk; na.bias[2] = bv; na.bias[3] = bskip;
  na.outp[0] = qb; na.outp[1] = kbuf; na.outp[2] = vbuf; na.outp[3] = out;
  const int node_tiles = (N + 15) / 16;
  k_node<<<(node_tiles + 3) / 4, 256, 0, stream>>>(x, feats, na, N);

  const int edge_tiles = (E + 15) / 16;
  k_egemm<<<(edge_tiles + 3) / 4, 256, 0, stream>>>(lu, ei, t, msg, tw, tb,
                                                    wfrag, rank, e_s, E);
  k_agg<<<(N + 3) / 4, 256, 0, stream>>>(offs, src_s, e_s, qb, kbuf, vbuf,
                                         out, N);
}